// Round 1
// baseline (1253.762 us; speedup 1.0000x reference)
//
#include <hip/hip_runtime.h>
#include <math.h>

// Problem constants
constexpr int BB = 2;      // batch
constexpr int SS = 2048;   // seq
constexpr int DD = 1024;   // model dim
constexpr int HH = 16;     // heads
constexpr int DCC = 16;    // coord dim per head
constexpr int DHH = 64;    // head dim

// ---------------------------------------------------------------------------
// GEMM: C[m,n] = sum_k A[m,k] * Wt[n,k] + bias[n]   (M=4096, N=1024, K=1024)
// EPI=0: scatter to V layout [B,H,S,DH];  EPI=1: plain row-major [M,N]
// ---------------------------------------------------------------------------
template <int EPI>
__global__ __launch_bounds__(256) void gemm_nt64(const float* __restrict__ A,
                                                 const float* __restrict__ Wt,
                                                 const float* __restrict__ bias,
                                                 float* __restrict__ C) {
    constexpr int K = 1024;
    __shared__ float As[16][64];
    __shared__ float Bs[16][64];
    const int tid = threadIdx.x;
    const int mBase = blockIdx.y * 64, nBase = blockIdx.x * 64;
    const int ty = tid >> 4, tx = tid & 15;   // 16x16 threads, each 4x4 outputs
    const int lr = tid >> 2, lc = tid & 3;    // loader: row 0..63, float4 col 0..3

    float acc[4][4] = {};
    for (int kk = 0; kk < K; kk += 16) {
        const float4 a4 = *(const float4*)(A  + (size_t)(mBase + lr) * K + kk + lc * 4);
        const float4 b4 = *(const float4*)(Wt + (size_t)(nBase + lr) * K + kk + lc * 4);
        __syncthreads();   // previous-iteration compute done before overwrite
        As[lc * 4 + 0][lr] = a4.x; As[lc * 4 + 1][lr] = a4.y;
        As[lc * 4 + 2][lr] = a4.z; As[lc * 4 + 3][lr] = a4.w;
        Bs[lc * 4 + 0][lr] = b4.x; Bs[lc * 4 + 1][lr] = b4.y;
        Bs[lc * 4 + 2][lr] = b4.z; Bs[lc * 4 + 3][lr] = b4.w;
        __syncthreads();
#pragma unroll
        for (int k = 0; k < 16; k++) {
            float av[4], bv4[4];
            *(float4*)av  = *(const float4*)&As[k][ty * 4];
            *(float4*)bv4 = *(const float4*)&Bs[k][tx * 4];
#pragma unroll
            for (int i = 0; i < 4; i++)
#pragma unroll
                for (int j = 0; j < 4; j++)
                    acc[i][j] = fmaf(av[i], bv4[j], acc[i][j]);
        }
    }

#pragma unroll
    for (int i = 0; i < 4; i++) {
#pragma unroll
        for (int j = 0; j < 4; j++) {
            const int m = mBase + ty * 4 + i;
            const int n = nBase + tx * 4 + j;
            const float v = acc[i][j] + bias[n];
            if (EPI == 0) {
                const int b = m >> 11, s = m & (SS - 1);
                const int h = n >> 6, dh = n & 63;
                C[(((size_t)(b * HH + h) * SS) + s) * DHH + dh] = v;
            } else {
                C[(size_t)m * DD + n] = v;
            }
        }
    }
}

// ---------------------------------------------------------------------------
// z = coords @ Wc.T + bc  -> Z [B,H,S,DC]  and  ZSQ [B,H,S]
// one block per (b,s); 256 threads = 16 heads x 16 coords
// ---------------------------------------------------------------------------
__global__ __launch_bounds__(256) void zker(const float* __restrict__ coords,
                                            const float* __restrict__ Wc,
                                            const float* __restrict__ bc,
                                            float* __restrict__ Z,
                                            float* __restrict__ ZSQ) {
    const int bs = blockIdx.x;
    const int b = bs >> 11, s = bs & (SS - 1);
    const int tid = threadIdx.x;
    __shared__ float csh[16];
    __shared__ float zl[256];
    if (tid < 16) csh[tid] = coords[(size_t)bs * 16 + tid];
    __syncthreads();
    float acc = bc[tid];
#pragma unroll
    for (int k = 0; k < 16; k++) acc = fmaf(csh[k], Wc[tid * 16 + k], acc);
    zl[tid] = acc;
    const int h = tid >> 4, c = tid & 15;
    Z[(((size_t)(b * HH + h) * SS) + s) * DCC + c] = acc;
    __syncthreads();
    if (tid < 16) {
        float sq = 0.f;
#pragma unroll
        for (int i = 0; i < 16; i++) { const float v = zl[tid * 16 + i]; sq += v * v; }
        ZSQ[(size_t)(b * HH + tid) * SS + s] = sq;
    }
}

// ---------------------------------------------------------------------------
// Fused flash attention (fp32):
//   scores s_t = -g * max(zsq_q + zsq_t - 2*z_q.z_t, 0), softmax over t,
//   out = attn @ V.  One block per (b, h, 64-query tile); 4 waves x 16 queries.
//   Lane = key within a 64-key chunk; PV broadcasts p via readlane.
// ---------------------------------------------------------------------------
__global__ __launch_bounds__(256, 3) void attn_fa(const float* __restrict__ Z,
                                                  const float* __restrict__ ZSQ,
                                                  const float* __restrict__ V,
                                                  const float* __restrict__ gamma,
                                                  float* __restrict__ AO) {
    __shared__ float zq[64][20];
    __shared__ float zsqq[64];
    __shared__ float zk[64][20];
    __shared__ float zsqk_s[64];
    __shared__ float Vs[64][64];

    const int qb = blockIdx.x, h = blockIdx.y, b = blockIdx.z;
    const int tid = threadIdx.x, w = tid >> 6, lane = tid & 63;

    const float* Zbh  = Z   + ((size_t)(b * HH + h) * SS) * DCC;
    const float* ZSbh = ZSQ +  (size_t)(b * HH + h) * SS;
    const float* Vbh  = V   + ((size_t)(b * HH + h) * SS) * DHH;

    const float gm = gamma[h];
    const float g = fmaxf(gm, 0.f) + log1pf(expf(-fabsf(gm)));  // softplus

    {   // stage query-tile z
        const int r = tid >> 2, c4 = (tid & 3) * 4;
        *(float4*)&zq[r][c4] = *(const float4*)(Zbh + (size_t)(qb * 64 + r) * DCC + c4);
        if (tid < 64) zsqq[tid] = ZSbh[qb * 64 + tid];
    }

    float m[16], l[16], acc[16], p[16];
#pragma unroll
    for (int q = 0; q < 16; q++) { m[q] = -1e30f; l[q] = 0.f; acc[q] = 0.f; }

    for (int kb = 0; kb < SS / 64; kb++) {
        __syncthreads();   // prev-iter reads done (also fences the zq staging)
        {   // stage key-chunk z, zsq, V
            const int r = tid >> 2, c4 = (tid & 3) * 4;
            *(float4*)&zk[r][c4] = *(const float4*)(Zbh + (size_t)(kb * 64 + r) * DCC + c4);
            if (tid < 64) zsqk_s[tid] = ZSbh[kb * 64 + tid];
#pragma unroll
            for (int i = 0; i < 4; i++) {
                const int e = tid + i * 256;
                const int vr = e >> 4, vc = (e & 15) * 4;
                *(float4*)&Vs[vr][vc] = *(const float4*)(Vbh + (size_t)(kb * 64 + vr) * DHH + vc);
            }
        }
        __syncthreads();

        float zkr[16];
#pragma unroll
        for (int c4 = 0; c4 < 16; c4 += 4)
            *(float4*)&zkr[c4] = *(const float4*)&zk[lane][c4];
        const float zsqk = zsqk_s[lane];

        // phase 1: scores + online softmax for this wave's 16 queries
#pragma unroll
        for (int q = 0; q < 16; q++) {
            const int qq = w * 16 + q;
            float zqr[16];
#pragma unroll
            for (int c4 = 0; c4 < 16; c4 += 4)
                *(float4*)&zqr[c4] = *(const float4*)&zq[qq][c4];
            float dot = 0.f;
#pragma unroll
            for (int c = 0; c < 16; c++) dot = fmaf(zkr[c], zqr[c], dot);
            float dv = zsqq[qq] + zsqk - 2.f * dot;
            dv = fmaxf(dv, 0.f);
            const float s = -g * dv;

            float mx = s;
#pragma unroll
            for (int off = 32; off > 0; off >>= 1) mx = fmaxf(mx, __shfl_xor(mx, off, 64));
            const float mnew = fmaxf(m[q], mx);
            const float pq = __expf(s - mnew);
            float ps = pq;
#pragma unroll
            for (int off = 32; off > 0; off >>= 1) ps += __shfl_xor(ps, off, 64);
            const float corr = __expf(m[q] - mnew);
            l[q] = fmaf(l[q], corr, ps);
            acc[q] *= corr;
            m[q] = mnew;
            p[q] = pq;
        }

        // phase 2: acc[q] += sum_t p[t][q] * V[t][lane]  (p broadcast via readlane)
#pragma unroll 8
        for (int t = 0; t < 64; t++) {
            const float v = Vs[t][lane];
#pragma unroll
            for (int q = 0; q < 16; q++) {
                const float pq = __uint_as_float(
                    __builtin_amdgcn_readlane(__float_as_uint(p[q]), t));
                acc[q] = fmaf(pq, v, acc[q]);
            }
        }
    }

    // epilogue: AO[b, s, h*64 + dh]  (dh = lane)
    const int s0 = qb * 64 + w * 16;
    float* AObase = AO + ((size_t)b * SS) * DD + (size_t)h * DHH + lane;
#pragma unroll
    for (int q = 0; q < 16; q++)
        AObase[(size_t)(s0 + q) * DD] = acc[q] / l[q];
}

// ---------------------------------------------------------------------------
// updated_coords = hidden @ Wn.T + bn   (4096 x 16, K=1024)
// ---------------------------------------------------------------------------
__global__ __launch_bounds__(256) void coords_out(const float* __restrict__ hs,
                                                  const float* __restrict__ Wn,
                                                  const float* __restrict__ bn,
                                                  float* __restrict__ out1) {
    const int e = blockIdx.x * 256 + threadIdx.x;   // 65536 outputs
    const int c = e & 15, bs = e >> 4;
    const float4* hrow = (const float4*)(hs + (size_t)bs * DD);
    const float4* wrow = (const float4*)(Wn + (size_t)c * DD);
    float acc = 0.f;
    for (int k = 0; k < DD / 4; k++) {
        const float4 h4 = hrow[k], w4 = wrow[k];
        acc = fmaf(h4.x, w4.x, fmaf(h4.y, w4.y, fmaf(h4.z, w4.z, fmaf(h4.w, w4.w, acc))));
    }
    out1[e] = acc + bn[c];
}

// ---------------------------------------------------------------------------
extern "C" void kernel_launch(void* const* d_in, const int* in_sizes, int n_in,
                              void* d_out, int out_size, void* d_ws, size_t ws_size,
                              hipStream_t stream) {
    (void)in_sizes; (void)n_in; (void)out_size; (void)ws_size;
    const float* hidden = (const float*)d_in[0];
    const float* coords = (const float*)d_in[1];
    const float* Wv     = (const float*)d_in[2];
    const float* bv     = (const float*)d_in[3];
    const float* Wc     = (const float*)d_in[4];
    const float* bc     = (const float*)d_in[5];
    const float* Wn     = (const float*)d_in[6];
    const float* bn     = (const float*)d_in[7];
    const float* Wo     = (const float*)d_in[8];
    const float* bo     = (const float*)d_in[9];
    const float* gamma  = (const float*)d_in[10];

    float* ws  = (float*)d_ws;
    float* V   = ws;                    // [B,H,S,DH]  4,194,304 floats
    float* Z   = V + 4194304;           // [B,H,S,DC]  1,048,576
    float* ZSQ = Z + 1048576;           // [B,H,S]        65,536
    float* AO  = ZSQ + 65536;           // [B,S,D]     4,194,304

    float* out_hidden = (float*)d_out;              // [B,S,D]
    float* out_coords = out_hidden + 4194304;       // [B,S,CD]

    gemm_nt64<0><<<dim3(16, 64), 256, 0, stream>>>(hidden, Wv, bv, V);
    zker<<<BB * SS, 256, 0, stream>>>(coords, Wc, bc, Z, ZSQ);
    attn_fa<<<dim3(SS / 64, HH, BB), 256, 0, stream>>>(Z, ZSQ, V, gamma, AO);
    gemm_nt64<1><<<dim3(16, 64), 256, 0, stream>>>(AO, Wo, bo, out_hidden);
    coords_out<<<256, 256, 0, stream>>>(hidden, Wn, bn, out_coords);
}

// Round 2
// 244.094 us; speedup vs baseline: 5.1364x; 5.1364x over previous
//
#include <hip/hip_runtime.h>
#include <math.h>

// Problem constants: B=2, S=2048, D=1024, H=16, DC=16, DH=64
typedef short short8 __attribute__((ext_vector_type(8)));
typedef float f32x4  __attribute__((ext_vector_type(4)));

__device__ __forceinline__ unsigned cvt_pk_bf16(float lo, float hi) {
    unsigned r;
    asm("v_cvt_pk_bf16_f32 %0, %1, %2" : "=v"(r) : "v"(lo), "v"(hi));
    return r;
}
__device__ __forceinline__ unsigned f2bf_rne(float x) {
    unsigned u = __float_as_uint(x);
    return (u + 0x7fffu + ((u >> 16) & 1u)) >> 16;
}

// ---------------------------------------------------------------------------
// fp32 -> bf16 bulk convert (8 elems/thread)
// ---------------------------------------------------------------------------
__global__ __launch_bounds__(256) void f2bf_kernel(const float* __restrict__ in,
                                                   short* __restrict__ out, int n8) {
    const int i = blockIdx.x * 256 + threadIdx.x;
    if (i >= n8) return;
    const float4 a = ((const float4*)in)[2 * i];
    const float4 b = ((const float4*)in)[2 * i + 1];
    uint4 r;
    r.x = cvt_pk_bf16(a.x, a.y);
    r.y = cvt_pk_bf16(a.z, a.w);
    r.z = cvt_pk_bf16(b.x, b.y);
    r.w = cvt_pk_bf16(b.z, b.w);
    ((uint4*)out)[i] = r;
}

// ---------------------------------------------------------------------------
// z = coords @ Wc.T + bc -> Ztp bf16 [b,h,s,32] (coords 16 real + 16 zero pad)
// and ZSQ fp32 [b*h, s] (sum of squares of the bf16-rounded z)
// ---------------------------------------------------------------------------
__global__ __launch_bounds__(256) void zker2(const float* __restrict__ coords,
                                             const float* __restrict__ Wc,
                                             const float* __restrict__ bc,
                                             short* __restrict__ Ztp,
                                             float* __restrict__ ZSQ) {
    const int bs = blockIdx.x;
    const int b = bs >> 11, s = bs & 2047;
    const int tid = threadIdx.x;
    __shared__ float csh[16];
    __shared__ float zl[256];
    if (tid < 16) csh[tid] = coords[(size_t)bs * 16 + tid];
    __syncthreads();
    float acc = bc[tid];
#pragma unroll
    for (int k = 0; k < 16; k++) acc = fmaf(csh[k], Wc[tid * 16 + k], acc);
    const unsigned ub = f2bf_rne(acc);
    const float zr = __uint_as_float(ub << 16);
    zl[tid] = zr;
    const int h = tid >> 4, c = tid & 15;
    const size_t base = ((size_t)(b * 16 + h) * 2048 + s) * 32;
    Ztp[base + c] = (short)ub;
    Ztp[base + 16 + c] = 0;
    __syncthreads();
    if (tid < 16) {
        float sq = 0.f;
#pragma unroll
        for (int i = 0; i < 16; i++) { const float v = zl[tid * 16 + i]; sq = fmaf(v, v, sq); }
        ZSQ[(size_t)(b * 16 + tid) * 2048 + s] = sq;
    }
}

// ---------------------------------------------------------------------------
// bf16 MFMA GEMM: C[m,n] = sum_k A[m,k]*W[n,k] + bias[n].  M=4096,N=1024,K=1024
// block: 256 thr = 4 waves, tile m 256 x n 32; per-wave 64x32 (4 m-tiles, 2 n-tiles)
// EPI=0: write V^T bf16 [b,h,dh,s];  EPI=1: write fp32 row-major [m,n]
// ---------------------------------------------------------------------------
template <int EPI>
__global__ __launch_bounds__(256) void gemm_bf(const short* __restrict__ A,
                                               const short* __restrict__ W,
                                               const float* __restrict__ bias,
                                               void* __restrict__ Cout) {
    const int tid = threadIdx.x;
    const int wv = tid >> 6, l = tid & 63, g = l >> 4, c = l & 15;
    const int mW = blockIdx.y * 256 + wv * 64;
    const int nB = blockIdx.x * 32;

    f32x4 acc[4][2] = {};
    for (int k0 = 0; k0 < 1024; k0 += 32) {
        short8 af[4], bfr[2];
#pragma unroll
        for (int mt = 0; mt < 4; mt++)
            af[mt] = *(const short8*)(A + (size_t)(mW + mt * 16 + c) * 1024 + k0 + g * 8);
#pragma unroll
        for (int nt = 0; nt < 2; nt++)
            bfr[nt] = *(const short8*)(W + (size_t)(nB + nt * 16 + c) * 1024 + k0 + g * 8);
#pragma unroll
        for (int mt = 0; mt < 4; mt++)
#pragma unroll
            for (int nt = 0; nt < 2; nt++)
                acc[mt][nt] = __builtin_amdgcn_mfma_f32_16x16x32_bf16(af[mt], bfr[nt], acc[mt][nt], 0, 0, 0);
    }
    const float b0 = bias[nB + c], b1 = bias[nB + 16 + c];
#pragma unroll
    for (int mt = 0; mt < 4; mt++) {
#pragma unroll
        for (int nt = 0; nt < 2; nt++) {
            const int m0 = mW + mt * 16 + g * 4;     // rows m0..m0+3 (reg v)
            const int n = nB + nt * 16 + c;
            f32x4 v = acc[mt][nt];
            v = v + (nt ? b1 : b0);
            if (EPI == 0) {
                const int b = m0 >> 11, s0 = m0 & 2047;
                const int hh = n >> 6, dh = n & 63;
                uint2 p2;
                p2.x = cvt_pk_bf16(v.x, v.y);
                p2.y = cvt_pk_bf16(v.z, v.w);
                *(uint2*)((short*)Cout + (size_t)((b * 16 + hh) * 64 + dh) * 2048 + s0) = p2;
            } else {
                float* C = (float*)Cout;
#pragma unroll
                for (int i = 0; i < 4; i++) C[(size_t)(m0 + i) * 1024 + n] = v[i];
            }
        }
    }
}

// ---------------------------------------------------------------------------
// Fused MFMA flash attention.
// Scores: D[key][query] = mfma(A=z_k, B=z_q) over padded K=32 coords.
// Softmax over keys = per-lane reduce over 16 regs + shfl_xor(16,32).
// PV: out^T[dh][q] = mfma(A=V^T, B=P); P redistributed D-layout -> B-frag via
// cvt_pk + 8 shfl per k-step (closed-form lane mapping, no LDS).
// Grid: (16 qblocks, 16 h, 2 b), 4 waves/block, each wave owns 32 queries.
// ---------------------------------------------------------------------------
__global__ __launch_bounds__(256) void attn_mfma(const short* __restrict__ Ztp,
                                                 const float* __restrict__ ZSQ,
                                                 const short* __restrict__ Vt,
                                                 const float* __restrict__ gamma,
                                                 short* __restrict__ AOb) {
    const int tid = threadIdx.x;
    const int wv = tid >> 6, l = tid & 63, g = l >> 4, qc = l & 15;
    const int h = blockIdx.y, b = blockIdx.z;
    const int bh = b * 16 + h;
    const int q0 = blockIdx.x * 128 + wv * 32;

    const float gm = gamma[h];
    const float gg = fmaxf(gm, 0.f) + log1pf(__expf(-fabsf(gm)));  // softplus
    const float g2 = 2.f * gg;

    const short* Zb = Ztp + (size_t)bh * (2048 * 32);
    const float* Qs = ZSQ + (size_t)bh * 2048;
    const short* Vb = Vt + (size_t)bh * (64 * 2048);

    short8 zq[2];
    float gq[2];
#pragma unroll
    for (int qt = 0; qt < 2; qt++) {
        zq[qt] = *(const short8*)(Zb + (size_t)(q0 + qt * 16 + qc) * 32 + g * 8);
        gq[qt] = -gg * Qs[q0 + qt * 16 + qc];
    }

    float mrun[2] = {-1e30f, -1e30f}, lrun[2] = {0.f, 0.f};
    f32x4 acc[4][2] = {};

    for (int kb = 0; kb < 2048; kb += 64) {
        // ---- loads (all L2-resident) ----
        short8 zk[4];
        f32x4 gk[4];
#pragma unroll
        for (int kt = 0; kt < 4; kt++) {
            zk[kt] = *(const short8*)(Zb + (size_t)(kb + kt * 16 + qc) * 32 + g * 8);
            gk[kt] = *(const f32x4*)(Qs + kb + kt * 16 + g * 4) * (-gg);
        }
        short8 vf[2][4];
#pragma unroll
        for (int s2 = 0; s2 < 2; s2++)
#pragma unroll
            for (int mt = 0; mt < 4; mt++)
                vf[s2][mt] = *(const short8*)(Vb + (size_t)(mt * 16 + qc) * 2048 + kb + s2 * 32 + g * 8);

        // ---- scores: S[kt][qt] = z_k . z_q (16 keys x 16 queries each) ----
        f32x4 S[4][2];
        const f32x4 z4 = {0.f, 0.f, 0.f, 0.f};
#pragma unroll
        for (int kt = 0; kt < 4; kt++)
#pragma unroll
            for (int qt = 0; qt < 2; qt++)
                S[kt][qt] = __builtin_amdgcn_mfma_f32_16x16x32_bf16(zk[kt], zq[qt], z4, 0, 0, 0);

        // ---- online softmax (s = min(2g*dot - g*(zsq_k+zsq_q), 0)) ----
        unsigned pk[2][4][2];
#pragma unroll
        for (int qt = 0; qt < 2; qt++) {
            float sv[4][4];
            float mx = -1e30f;
#pragma unroll
            for (int kt = 0; kt < 4; kt++)
#pragma unroll
                for (int v = 0; v < 4; v++) {
                    const float s = fminf(fmaf(g2, S[kt][qt][v], gk[kt][v] + gq[qt]), 0.f);
                    sv[kt][v] = s;
                    mx = fmaxf(mx, s);
                }
            mx = fmaxf(mx, __shfl_xor(mx, 16, 64));
            mx = fmaxf(mx, __shfl_xor(mx, 32, 64));
            const float mnew = fmaxf(mrun[qt], mx);
            const float scale = __expf(mrun[qt] - mnew);
            mrun[qt] = mnew;
            float ls = 0.f;
#pragma unroll
            for (int kt = 0; kt < 4; kt++) {
#pragma unroll
                for (int v = 0; v < 4; v++) {
                    sv[kt][v] = __expf(sv[kt][v] - mnew);
                    ls += sv[kt][v];
                }
                pk[qt][kt][0] = cvt_pk_bf16(sv[kt][0], sv[kt][1]);
                pk[qt][kt][1] = cvt_pk_bf16(sv[kt][2], sv[kt][3]);
            }
            ls += __shfl_xor(ls, 16, 64);
            ls += __shfl_xor(ls, 32, 64);
            lrun[qt] = fmaf(lrun[qt], scale, ls);
#pragma unroll
            for (int mt = 0; mt < 4; mt++) acc[mt][qt] = acc[mt][qt] * scale;
        }

        // ---- PV: acc[mt][qt] += V^T-frag x P-frag ----
#pragma unroll
        for (int s2 = 0; s2 < 2; s2++) {
#pragma unroll
            for (int qt = 0; qt < 2; qt++) {
                union { unsigned u[4]; short8 v8; } bfr;
#pragma unroll
                for (int w2 = 0; w2 < 4; w2++) {
                    const int src = qc + 16 * (((g & 1) << 1) + (w2 >> 1));
                    const int wi = w2 & 1;
                    const unsigned u0 = (unsigned)__shfl((int)pk[qt][s2 * 2 + 0][wi], src, 64);
                    const unsigned u1 = (unsigned)__shfl((int)pk[qt][s2 * 2 + 1][wi], src, 64);
                    bfr.u[w2] = (g >> 1) ? u1 : u0;
                }
#pragma unroll
                for (int mt = 0; mt < 4; mt++)
                    acc[mt][qt] = __builtin_amdgcn_mfma_f32_16x16x32_bf16(vf[s2][mt], bfr.v8, acc[mt][qt], 0, 0, 0);
            }
        }
    }

    // ---- epilogue: AOb[b, q, h*64+dh] bf16, dh = mt*16 + g*4 + v ----
#pragma unroll
    for (int qt = 0; qt < 2; qt++) {
        const float inv = 1.f / lrun[qt];
        const size_t row = (size_t)(b * 2048 + q0 + qt * 16 + qc) * 1024 + h * 64;
#pragma unroll
        for (int mt = 0; mt < 4; mt++) {
            uint2 o;
            o.x = cvt_pk_bf16(acc[mt][qt][0] * inv, acc[mt][qt][1] * inv);
            o.y = cvt_pk_bf16(acc[mt][qt][2] * inv, acc[mt][qt][3] * inv);
            *(uint2*)(AOb + row + mt * 16 + g * 4) = o;
        }
    }
}

// ---------------------------------------------------------------------------
// updated_coords = hidden @ Wn.T + bn  (fp32, exact)
// ---------------------------------------------------------------------------
__global__ __launch_bounds__(256) void coords_out(const float* __restrict__ hs,
                                                  const float* __restrict__ Wn,
                                                  const float* __restrict__ bn,
                                                  float* __restrict__ out1) {
    const int e = blockIdx.x * 256 + threadIdx.x;
    const int c = e & 15, bs = e >> 4;
    const float4* hrow = (const float4*)(hs + (size_t)bs * 1024);
    const float4* wrow = (const float4*)(Wn + (size_t)c * 1024);
    float acc = 0.f;
    for (int k = 0; k < 256; k++) {
        const float4 h4 = hrow[k], w4 = wrow[k];
        acc = fmaf(h4.x, w4.x, fmaf(h4.y, w4.y, fmaf(h4.z, w4.z, fmaf(h4.w, w4.w, acc))));
    }
    out1[e] = acc + bn[c];
}

// ---------------------------------------------------------------------------
extern "C" void kernel_launch(void* const* d_in, const int* in_sizes, int n_in,
                              void* d_out, int out_size, void* d_ws, size_t ws_size,
                              hipStream_t stream) {
    (void)in_sizes; (void)n_in; (void)out_size; (void)ws_size;
    const float* hidden = (const float*)d_in[0];
    const float* coords = (const float*)d_in[1];
    const float* Wv = (const float*)d_in[2];
    const float* bv = (const float*)d_in[3];
    const float* Wc = (const float*)d_in[4];
    const float* bc = (const float*)d_in[5];
    const float* Wn = (const float*)d_in[6];
    const float* bn = (const float*)d_in[7];
    const float* Wo = (const float*)d_in[8];
    const float* bo = (const float*)d_in[9];
    const float* gamma = (const float*)d_in[10];

    char* wsb = (char*)d_ws;
    short* hsb = (short*)(wsb);                    // 8 MB  [4096,1024] bf16
    short* Wvb = (short*)(wsb + (8 << 20));        // 2 MB
    short* Wob = (short*)(wsb + (10 << 20));       // 2 MB
    short* Vt  = (short*)(wsb + (12 << 20));       // 8 MB  [b,h,dh,s] bf16
    short* Ztp = (short*)(wsb + (20 << 20));       // 4 MB  [b,h,s,32] bf16
    float* ZSQ = (float*)(wsb + (24 << 20));       // 256 KB
    short* AOb = (short*)(wsb + (25 << 20));       // 8 MB  [b,s,d] bf16

    float* out_hidden = (float*)d_out;             // [B,S,D]
    float* out_coords = out_hidden + 4194304;      // [B,S,CD]

    f2bf_kernel<<<2048, 256, 0, stream>>>(hidden, hsb, 524288);
    f2bf_kernel<<<512, 256, 0, stream>>>(Wv, Wvb, 131072);
    f2bf_kernel<<<512, 256, 0, stream>>>(Wo, Wob, 131072);
    zker2<<<4096, 256, 0, stream>>>(coords, Wc, bc, Ztp, ZSQ);
    gemm_bf<0><<<dim3(32, 16), 256, 0, stream>>>(hsb, Wvb, bv, (void*)Vt);
    attn_mfma<<<dim3(16, 16, 2), 256, 0, stream>>>(Ztp, ZSQ, Vt, gamma, AOb);
    gemm_bf<1><<<dim3(32, 16), 256, 0, stream>>>(AOb, Wob, bo, (void*)out_hidden);
    coords_out<<<256, 256, 0, stream>>>(hidden, Wn, bn, out_coords);
}

// Round 3
// 184.472 us; speedup vs baseline: 6.7965x; 1.3232x over previous
//
#include <hip/hip_runtime.h>
#include <math.h>

// Problem constants: B=2, S=2048, D=1024, H=16, DC=16, DH=64
typedef short short8 __attribute__((ext_vector_type(8)));
typedef float f32x4  __attribute__((ext_vector_type(4)));

__device__ __forceinline__ unsigned cvt_pk_bf16(float lo, float hi) {
    unsigned r;
    asm("v_cvt_pk_bf16_f32 %0, %1, %2" : "=v"(r) : "v"(lo), "v"(hi));
    return r;
}
__device__ __forceinline__ unsigned f2bf_rne(float x) {
    unsigned u = __float_as_uint(x);
    return (u + 0x7fffu + ((u >> 16) & 1u)) >> 16;
}
__device__ __forceinline__ float exp2_fast(float x) {   // v_exp_f32 computes 2^x
    float r;
    asm("v_exp_f32 %0, %1" : "=v"(r) : "v"(x));
    return r;
}

// ---------------------------------------------------------------------------
// fp32 -> bf16 bulk convert (8 elems/thread)
// ---------------------------------------------------------------------------
__global__ __launch_bounds__(256) void f2bf_kernel(const float* __restrict__ in,
                                                   short* __restrict__ out, int n8) {
    const int i = blockIdx.x * 256 + threadIdx.x;
    if (i >= n8) return;
    const float4 a = ((const float4*)in)[2 * i];
    const float4 b = ((const float4*)in)[2 * i + 1];
    uint4 r;
    r.x = cvt_pk_bf16(a.x, a.y);
    r.y = cvt_pk_bf16(a.z, a.w);
    r.z = cvt_pk_bf16(b.x, b.y);
    r.w = cvt_pk_bf16(b.z, b.w);
    ((uint4*)out)[i] = r;
}

// both weight matrices in one launch (512 blocks each)
__global__ __launch_bounds__(256) void f2bfW(const float* __restrict__ Wv,
                                             const float* __restrict__ Wo,
                                             short* __restrict__ Wvb,
                                             short* __restrict__ Wob) {
    const int i = blockIdx.x * 256 + threadIdx.x;
    const float* src = (i < 131072) ? Wv : Wo;
    short* dst = (i < 131072) ? Wvb : Wob;
    const int ii = i & 131071;
    const float4 a = ((const float4*)src)[2 * ii];
    const float4 b = ((const float4*)src)[2 * ii + 1];
    uint4 r;
    r.x = cvt_pk_bf16(a.x, a.y);
    r.y = cvt_pk_bf16(a.z, a.w);
    r.z = cvt_pk_bf16(b.x, b.y);
    r.w = cvt_pk_bf16(b.z, b.w);
    ((uint4*)dst)[ii] = r;
}

// ---------------------------------------------------------------------------
// z = coords @ Wc.T + bc, per head h with ch = -softplus(gamma_h)*log2(e):
//   ZA[b,h,s,32] = [z(16), zsq, 1, 0...]          (keys / A-operand)
//   ZB[b,h,s,32] = [-2*ch*z(16), ch, ch*zsq, 0..] (queries / B-operand)
// => MFMA(ZA_k, ZB_q) = ch * (zsq_k + zsq_q - 2 z_k.z_q) = exp2 argument.
// one block per (b,s); 256 threads = 16 heads x 16 coords
// ---------------------------------------------------------------------------
__global__ __launch_bounds__(256) void zker3(const float* __restrict__ coords,
                                             const float* __restrict__ Wc,
                                             const float* __restrict__ bc,
                                             const float* __restrict__ gamma,
                                             short* __restrict__ ZA,
                                             short* __restrict__ ZB) {
    const int bs = blockIdx.x;
    const int b = bs >> 11, s = bs & 2047;
    const int tid = threadIdx.x;
    __shared__ float csh[16];
    if (tid < 16) csh[tid] = coords[(size_t)bs * 16 + tid];
    __syncthreads();
    float z = bc[tid];
#pragma unroll
    for (int k = 0; k < 16; k++) z = fmaf(csh[k], Wc[tid * 16 + k], z);
    const unsigned ub = f2bf_rne(z);
    const float zb = __uint_as_float(ub << 16);
    // zsq over the 16-lane coord group (threads h*16+c -> lanes grouped by 16)
    float sq = zb * zb;
    sq += __shfl_xor(sq, 1, 64);
    sq += __shfl_xor(sq, 2, 64);
    sq += __shfl_xor(sq, 4, 64);
    sq += __shfl_xor(sq, 8, 64);
    const int h = tid >> 4, c = tid & 15;
    const float gm = gamma[h];
    const float sp = fmaxf(gm, 0.f) + log1pf(__expf(-fabsf(gm)));  // softplus
    const float ch = -sp * 1.4426950408889634f;                    // -g*log2(e)
    const size_t row = ((size_t)(b * 16 + h) * 2048 + s) * 32;
    ZA[row + c] = (short)ub;
    ZA[row + 16 + c] = (c == 0) ? (short)f2bf_rne(sq)
                                : (c == 1 ? (short)0x3F80 : (short)0);
    ZB[row + c] = (short)f2bf_rne(-2.f * ch * zb);
    ZB[row + 16 + c] = (c == 0) ? (short)f2bf_rne(ch)
                                : (c == 1 ? (short)f2bf_rne(ch * sq) : (short)0);
}

// ---------------------------------------------------------------------------
// m97-style bf16 MFMA GEMM: C[m,n] = sum_k A[m,k]*W[n,k] + bias[n]
// M=4096, N=1024, K=1024.  128x128 tile, BK=32, 4 waves (2x2 of 64x64),
// double-buffered LDS staged via global_load_lds width 16.
// EPI=0: write V^T bf16 [b,h,dh,s];  EPI=1: fp32 row-major [m,n]
// ---------------------------------------------------------------------------
template <int EPI>
__global__ __launch_bounds__(256) void gemm_mfma(const short* __restrict__ A,
                                                 const short* __restrict__ W,
                                                 const float* __restrict__ bias,
                                                 void* __restrict__ Cout) {
    __shared__ short As[2][128][32];
    __shared__ short Bs[2][128][32];
    const int tid = threadIdx.x;
    const int wv = tid >> 6, l = tid & 63, g = l >> 4, qc = l & 15;
    const int wm = wv >> 1, wn = wv & 1;
    const int Mb = blockIdx.y * 128, Nb = blockIdx.x * 128;

    auto stage = [&](int buf, int k0) {
        const short* ga = A + (size_t)Mb * 1024 + k0;
        const short* gb = W + (size_t)Nb * 1024 + k0;
#pragma unroll
        for (int i = 0; i < 2; i++) {
            const int c = i * 256 + tid;          // chunk id 0..511
            const int r = c >> 2, j = c & 3;      // row, 16B-chunk in row
            const short* gsA = ga + (size_t)r * 1024 + j * 8;
            const short* gsB = gb + (size_t)r * 1024 + j * 8;
            short* ldsA = &As[buf][0][0] + (size_t)(i * 256 + wv * 64) * 8;  // wave-uniform
            short* ldsB = &Bs[buf][0][0] + (size_t)(i * 256 + wv * 64) * 8;
            __builtin_amdgcn_global_load_lds((const __attribute__((address_space(1))) void*)gsA,
                                             (__attribute__((address_space(3))) void*)ldsA, 16, 0, 0);
            __builtin_amdgcn_global_load_lds((const __attribute__((address_space(1))) void*)gsB,
                                             (__attribute__((address_space(3))) void*)ldsB, 16, 0, 0);
        }
    };

    f32x4 acc[4][4] = {};
    stage(0, 0);
    __syncthreads();
    int cur = 0;
#pragma unroll 1
    for (int kb = 0; kb < 32; kb++) {
        if (kb < 31) stage(cur ^ 1, (kb + 1) * 32);
        short8 af[4], bfr[4];
#pragma unroll
        for (int mt = 0; mt < 4; mt++)
            af[mt] = *(const short8*)&As[cur][wm * 64 + mt * 16 + qc][g * 8];
#pragma unroll
        for (int nt = 0; nt < 4; nt++)
            bfr[nt] = *(const short8*)&Bs[cur][wn * 64 + nt * 16 + qc][g * 8];
#pragma unroll
        for (int mt = 0; mt < 4; mt++)
#pragma unroll
            for (int nt = 0; nt < 4; nt++)
                acc[mt][nt] = __builtin_amdgcn_mfma_f32_16x16x32_bf16(af[mt], bfr[nt], acc[mt][nt], 0, 0, 0);
        __syncthreads();
        cur ^= 1;
    }

    float bl[4];
#pragma unroll
    for (int nt = 0; nt < 4; nt++) bl[nt] = bias[Nb + wn * 64 + nt * 16 + qc];
#pragma unroll
    for (int mt = 0; mt < 4; mt++) {
#pragma unroll
        for (int nt = 0; nt < 4; nt++) {
            const int m0 = Mb + wm * 64 + mt * 16 + g * 4;
            const int n  = Nb + wn * 64 + nt * 16 + qc;
            f32x4 v = acc[mt][nt];
            v = v + bl[nt];
            if (EPI == 0) {
                const int bb = m0 >> 11, s0 = m0 & 2047;
                const int hh = n >> 6, dh = n & 63;
                uint2 p2;
                p2.x = cvt_pk_bf16(v[0], v[1]);
                p2.y = cvt_pk_bf16(v[2], v[3]);
                *(uint2*)((short*)Cout + (size_t)((bb * 16 + hh) * 64 + dh) * 2048 + s0) = p2;
            } else {
                float* C = (float*)Cout;
#pragma unroll
                for (int i = 0; i < 4; i++) C[(size_t)(m0 + i) * 1024 + n] = v[i];
            }
        }
    }
}

// ---------------------------------------------------------------------------
// Fused MFMA flash attention, simplified softmax:
//   S = MFMA(ZA_k, ZB_q) = c*dv  (c<0 folded per head), p = exp2(min(S,0)),
//   fixed m=0 (diagonal guarantees max score 0), l via ones-row MFMA.
// V and Z-key tiles staged in double-buffered LDS (shared by 4 waves),
// V tile XOR-swizzled ((r&7) on 16B chunk) for conflict-free b128 reads.
// Grid: (16 qblocks, 16 h, 2 b), 4 waves, 32 queries/wave.
// ---------------------------------------------------------------------------
__global__ __launch_bounds__(256) void attn_mfma2(const short* __restrict__ ZAg,
                                                  const short* __restrict__ ZBg,
                                                  const short* __restrict__ Vt,
                                                  short* __restrict__ AOb) {
    __shared__ short Vs[2][64][64];
    __shared__ short Zs[2][64][32];
    const int tid = threadIdx.x;
    const int wv = tid >> 6, l = tid & 63, g = l >> 4, qc = l & 15;
    const int h = blockIdx.y, b = blockIdx.z;
    const int bh = b * 16 + h;
    const int q0 = blockIdx.x * 128 + wv * 32;

    const short* ZAb = ZAg + (size_t)bh * (2048 * 32);
    const short* ZBb = ZBg + (size_t)bh * (2048 * 32);
    const short* Vb  = Vt  + (size_t)bh * (64 * 2048);

    short8 zq[2];
#pragma unroll
    for (int qt = 0; qt < 2; qt++)
        zq[qt] = *(const short8*)(ZBb + (size_t)(q0 + qt * 16 + qc) * 32 + g * 8);

    union { unsigned u[4]; short8 s8; } onesf;
    {
        const unsigned ow = (qc == 0) ? 0x3F803F80u : 0u;   // row 0 of A-tile = ones
        onesf.u[0] = ow; onesf.u[1] = ow; onesf.u[2] = ow; onesf.u[3] = ow;
    }

    f32x4 acc[4][2] = {};
    f32x4 accl[2] = {};

    // staging: V tile 64x64 (2 chunks/thread), Z tile 64x32 (1 chunk/thread)
    uint4 vr0, vr1, zr;
    const int v_r = tid >> 2, v_j = (tid & 3) * 2;   // chunks 2t,2t+1: row, chunk
    const int z_r = tid >> 2, z_j = tid & 3;

    auto tload = [&](int kb) {
        const short* p = Vb + (size_t)v_r * 2048 + kb + v_j * 8;
        vr0 = *(const uint4*)p;
        vr1 = *(const uint4*)(p + 8);
        zr = *(const uint4*)(ZAb + (size_t)(kb + z_r) * 32 + z_j * 8);
    };
    auto twrite = [&](int buf) {
        *(uint4*)&Vs[buf][v_r][(v_j ^ (v_r & 7)) * 8] = vr0;
        *(uint4*)&Vs[buf][v_r][((v_j + 1) ^ (v_r & 7)) * 8] = vr1;
        *(uint4*)&Zs[buf][z_r][z_j * 8] = zr;
    };

    tload(0);
    twrite(0);
    __syncthreads();
    int cur = 0;
#pragma unroll 1
    for (int kb = 0; kb < 2048; kb += 64) {
        const bool more = (kb + 64 < 2048);
        if (more) tload(kb + 64);   // issue early; written after compute

        short8 zk[4];
#pragma unroll
        for (int kt = 0; kt < 4; kt++)
            zk[kt] = *(const short8*)&Zs[cur][kt * 16 + qc][g * 8];

        const f32x4 z4 = {0.f, 0.f, 0.f, 0.f};
        f32x4 S[4][2];
#pragma unroll
        for (int kt = 0; kt < 4; kt++)
#pragma unroll
            for (int qt = 0; qt < 2; qt++)
                S[kt][qt] = __builtin_amdgcn_mfma_f32_16x16x32_bf16(zk[kt], zq[qt], z4, 0, 0, 0);

        short8 vf[2][4];
#pragma unroll
        for (int s2 = 0; s2 < 2; s2++)
#pragma unroll
            for (int mt = 0; mt < 4; mt++)
                vf[s2][mt] = *(const short8*)&Vs[cur][mt * 16 + qc][((s2 * 4 + g) ^ (qc & 7)) * 8];

        // p = exp2(min(S,0)); pack to bf16 pairs
        unsigned pk[2][4][2];
#pragma unroll
        for (int qt = 0; qt < 2; qt++)
#pragma unroll
            for (int kt = 0; kt < 4; kt++) {
                const float p0 = exp2_fast(fminf(S[kt][qt][0], 0.f));
                const float p1 = exp2_fast(fminf(S[kt][qt][1], 0.f));
                const float p2 = exp2_fast(fminf(S[kt][qt][2], 0.f));
                const float p3 = exp2_fast(fminf(S[kt][qt][3], 0.f));
                pk[qt][kt][0] = cvt_pk_bf16(p0, p1);
                pk[qt][kt][1] = cvt_pk_bf16(p2, p3);
            }

        // PV + l accumulation (D-layout -> B-frag redistribution, 8 shfl + 4 sel)
#pragma unroll
        for (int s2 = 0; s2 < 2; s2++)
#pragma unroll
            for (int qt = 0; qt < 2; qt++) {
                union { unsigned u[4]; short8 v8; } bfr;
#pragma unroll
                for (int w2 = 0; w2 < 4; w2++) {
                    const int src = qc + 16 * (((g & 1) << 1) + (w2 >> 1));
                    const int wi = w2 & 1;
                    const unsigned u0 = (unsigned)__shfl((int)pk[qt][s2 * 2 + 0][wi], src, 64);
                    const unsigned u1 = (unsigned)__shfl((int)pk[qt][s2 * 2 + 1][wi], src, 64);
                    bfr.u[w2] = (g >> 1) ? u1 : u0;
                }
                accl[qt] = __builtin_amdgcn_mfma_f32_16x16x32_bf16(onesf.s8, bfr.v8, accl[qt], 0, 0, 0);
#pragma unroll
                for (int mt = 0; mt < 4; mt++)
                    acc[mt][qt] = __builtin_amdgcn_mfma_f32_16x16x32_bf16(vf[s2][mt], bfr.v8, acc[mt][qt], 0, 0, 0);
            }

        if (more) twrite(cur ^ 1);
        __syncthreads();
        cur ^= 1;
    }

    // epilogue: l sits at D(row0,col qc) = lane qc, reg 0
#pragma unroll
    for (int qt = 0; qt < 2; qt++) {
        const float lv = __shfl(accl[qt][0], qc, 64);
        const float inv = 1.f / lv;
        const size_t row = (size_t)(b * 2048 + q0 + qt * 16 + qc) * 1024 + h * 64;
#pragma unroll
        for (int mt = 0; mt < 4; mt++) {
            uint2 o;
            o.x = cvt_pk_bf16(acc[mt][qt][0] * inv, acc[mt][qt][1] * inv);
            o.y = cvt_pk_bf16(acc[mt][qt][2] * inv, acc[mt][qt][3] * inv);
            *(uint2*)(AOb + row + mt * 16 + g * 4) = o;
        }
    }
}

// ---------------------------------------------------------------------------
// updated_coords = hidden @ Wn.T + bn (fp32 exact); 4 threads per output
// ---------------------------------------------------------------------------
__global__ __launch_bounds__(256) void coords_out2(const float* __restrict__ hs,
                                                   const float* __restrict__ Wn,
                                                   const float* __restrict__ bn,
                                                   float* __restrict__ out1) {
    const int gid = blockIdx.x * 256 + threadIdx.x;
    const int e = gid >> 2, sub = gid & 3;
    const int c = e & 15, bs = e >> 4;
    const float4* hrow = (const float4*)(hs + (size_t)bs * 1024) + sub * 64;
    const float4* wrow = (const float4*)(Wn + (size_t)c * 1024) + sub * 64;
    float acc = 0.f;
#pragma unroll 4
    for (int k = 0; k < 64; k++) {
        const float4 h4 = hrow[k], w4 = wrow[k];
        acc = fmaf(h4.x, w4.x, fmaf(h4.y, w4.y, fmaf(h4.z, w4.z, fmaf(h4.w, w4.w, acc))));
    }
    acc += __shfl_xor(acc, 1, 64);
    acc += __shfl_xor(acc, 2, 64);
    if (sub == 0) out1[e] = acc + bn[c];
}

// ---------------------------------------------------------------------------
extern "C" void kernel_launch(void* const* d_in, const int* in_sizes, int n_in,
                              void* d_out, int out_size, void* d_ws, size_t ws_size,
                              hipStream_t stream) {
    (void)in_sizes; (void)n_in; (void)out_size; (void)ws_size;
    const float* hidden = (const float*)d_in[0];
    const float* coords = (const float*)d_in[1];
    const float* Wv = (const float*)d_in[2];
    const float* bv = (const float*)d_in[3];
    const float* Wc = (const float*)d_in[4];
    const float* bc = (const float*)d_in[5];
    const float* Wn = (const float*)d_in[6];
    const float* bn = (const float*)d_in[7];
    const float* Wo = (const float*)d_in[8];
    const float* bo = (const float*)d_in[9];
    const float* gamma = (const float*)d_in[10];

    char* wsb = (char*)d_ws;
    short* hsb = (short*)(wsb);                    // 0..8 MB  [4096,1024] bf16
    short* AOb = hsb;                              // aliases hsb (hsb dead after gemm<0>)
    short* Wvb = (short*)(wsb + (8 << 20));        // 8..10 MB
    short* Wob = (short*)(wsb + (10 << 20));       // 10..12 MB
    short* Vt  = (short*)(wsb + (12 << 20));       // 12..20 MB [b,h,dh,s] bf16
    short* ZA  = (short*)(wsb + (20 << 20));       // 20..24 MB [b,h,s,32] bf16
    short* ZB  = (short*)(wsb + (24 << 20));       // 24..28 MB [b,h,s,32] bf16

    float* out_hidden = (float*)d_out;             // [B,S,D]
    float* out_coords = out_hidden + 4194304;      // [B,S,CD]

    f2bf_kernel<<<2048, 256, 0, stream>>>(hidden, hsb, 524288);
    f2bfW<<<1024, 256, 0, stream>>>(Wv, Wo, Wvb, Wob);
    zker3<<<4096, 256, 0, stream>>>(coords, Wc, bc, gamma, ZA, ZB);
    gemm_mfma<0><<<dim3(8, 32), 256, 0, stream>>>(hsb, Wvb, bv, (void*)Vt);
    attn_mfma2<<<dim3(16, 16, 2), 256, 0, stream>>>(ZA, ZB, Vt, AOb);
    gemm_mfma<1><<<dim3(8, 32), 256, 0, stream>>>(AOb, Wob, bo, (void*)out_hidden);
    coords_out2<<<1024, 256, 0, stream>>>(hidden, Wn, bn, out_coords);
}

// Round 4
// 177.461 us; speedup vs baseline: 7.0650x; 1.0395x over previous
//
#include <hip/hip_runtime.h>
#include <math.h>

// Problem constants: B=2, S=2048, D=1024, H=16, DC=16, DH=64
typedef short short8 __attribute__((ext_vector_type(8)));
typedef float f32x4  __attribute__((ext_vector_type(4)));

__device__ __forceinline__ unsigned cvt_pk_bf16(float lo, float hi) {
    unsigned r;
    asm("v_cvt_pk_bf16_f32 %0, %1, %2" : "=v"(r) : "v"(lo), "v"(hi));
    return r;
}
__device__ __forceinline__ unsigned f2bf_rne(float x) {
    unsigned u = __float_as_uint(x);
    return (u + 0x7fffu + ((u >> 16) & 1u)) >> 16;
}
__device__ __forceinline__ float exp2_fast(float x) {   // v_exp_f32 computes 2^x
    float r;
    asm("v_exp_f32 %0, %1" : "=v"(r) : "v"(x));
    return r;
}

// ---------------------------------------------------------------------------
// fp32 -> bf16 bulk convert (8 elems/thread)
// ---------------------------------------------------------------------------
__global__ __launch_bounds__(256) void f2bf_kernel(const float* __restrict__ in,
                                                   short* __restrict__ out, int n8) {
    const int i = blockIdx.x * 256 + threadIdx.x;
    if (i >= n8) return;
    const float4 a = ((const float4*)in)[2 * i];
    const float4 b = ((const float4*)in)[2 * i + 1];
    uint4 r;
    r.x = cvt_pk_bf16(a.x, a.y);
    r.y = cvt_pk_bf16(a.z, a.w);
    r.z = cvt_pk_bf16(b.x, b.y);
    r.w = cvt_pk_bf16(b.z, b.w);
    ((uint4*)out)[i] = r;
}

// both weight matrices in one launch (512 blocks each)
__global__ __launch_bounds__(256) void f2bfW(const float* __restrict__ Wv,
                                             const float* __restrict__ Wo,
                                             short* __restrict__ Wvb,
                                             short* __restrict__ Wob) {
    const int i = blockIdx.x * 256 + threadIdx.x;
    const float* src = (i < 131072) ? Wv : Wo;
    short* dst = (i < 131072) ? Wvb : Wob;
    const int ii = i & 131071;
    const float4 a = ((const float4*)src)[2 * ii];
    const float4 b = ((const float4*)src)[2 * ii + 1];
    uint4 r;
    r.x = cvt_pk_bf16(a.x, a.y);
    r.y = cvt_pk_bf16(a.z, a.w);
    r.z = cvt_pk_bf16(b.x, b.y);
    r.w = cvt_pk_bf16(b.z, b.w);
    ((uint4*)dst)[ii] = r;
}

// ---------------------------------------------------------------------------
// z = coords @ Wc.T + bc, per head h with ch = -softplus(gamma_h)*log2(e):
//   ZA[b,h,s,32] = [z(16), zsq, 1, 0...]          (keys / A-operand)
//   ZB[b,h,s,32] = [-2*ch*z(16), ch, ch*zsq, 0..] (queries / B-operand)
// => MFMA(ZA_k, ZB_q) = ch * (zsq_k + zsq_q - 2 z_k.z_q) = exp2 argument.
// ---------------------------------------------------------------------------
__global__ __launch_bounds__(256) void zker3(const float* __restrict__ coords,
                                             const float* __restrict__ Wc,
                                             const float* __restrict__ bc,
                                             const float* __restrict__ gamma,
                                             short* __restrict__ ZA,
                                             short* __restrict__ ZB) {
    const int bs = blockIdx.x;
    const int b = bs >> 11, s = bs & 2047;
    const int tid = threadIdx.x;
    __shared__ float csh[16];
    if (tid < 16) csh[tid] = coords[(size_t)bs * 16 + tid];
    __syncthreads();
    float z = bc[tid];
#pragma unroll
    for (int k = 0; k < 16; k++) z = fmaf(csh[k], Wc[tid * 16 + k], z);
    const unsigned ub = f2bf_rne(z);
    const float zb = __uint_as_float(ub << 16);
    float sq = zb * zb;
    sq += __shfl_xor(sq, 1, 64);
    sq += __shfl_xor(sq, 2, 64);
    sq += __shfl_xor(sq, 4, 64);
    sq += __shfl_xor(sq, 8, 64);
    const int h = tid >> 4, c = tid & 15;
    const float gm = gamma[h];
    const float sp = fmaxf(gm, 0.f) + log1pf(__expf(-fabsf(gm)));  // softplus
    const float ch = -sp * 1.4426950408889634f;                    // -g*log2(e)
    const size_t row = ((size_t)(b * 16 + h) * 2048 + s) * 32;
    ZA[row + c] = (short)ub;
    ZA[row + 16 + c] = (c == 0) ? (short)f2bf_rne(sq)
                                : (c == 1 ? (short)0x3F80 : (short)0);
    ZB[row + c] = (short)f2bf_rne(-2.f * ch * zb);
    ZB[row + 16 + c] = (c == 0) ? (short)f2bf_rne(ch)
                                : (c == 1 ? (short)f2bf_rne(ch * sq) : (short)0);
}

// ---------------------------------------------------------------------------
// bf16 MFMA GEMM: C[m,n] = sum_k A[m,k]*W[n,k] + bias[n].  M=4096,N=1024,K=1024
// 128x64 tile (grid 512 = 2 blocks/CU), BK=32, 4 waves (2x2 of 64x32),
// double-buffered LDS via global_load_lds w16; chunk-XOR swizzle applied on
// the GLOBAL source (LDS dest linear, rule #21) + swizzled frag reads.
// EPI=0: write V^T bf16 [b,h,dh,s];  EPI=1: fp32 row-major [m,n]
// ---------------------------------------------------------------------------
template <int EPI>
__global__ __launch_bounds__(256) void gemm_mfma(const short* __restrict__ A,
                                                 const short* __restrict__ W,
                                                 const float* __restrict__ bias,
                                                 void* __restrict__ Cout) {
    __shared__ short As[2][128][32];
    __shared__ short Bs[2][64][32];
    const int tid = threadIdx.x;
    const int wv = tid >> 6, l = tid & 63, g = l >> 4, qc = l & 15;
    const int wm = wv >> 1, wn = wv & 1;
    const int Mb = blockIdx.y * 128, Nb = blockIdx.x * 64;

    auto stage = [&](int buf, int k0) {
        const short* ga = A + (size_t)Mb * 1024 + k0;
        const short* gb = W + (size_t)Nb * 1024 + k0;
#pragma unroll
        for (int i = 0; i < 2; i++) {
            const int c = i * 256 + tid;                 // A chunk id 0..511
            const int r = c >> 2, jp = c & 3;
            const int js = jp ^ ((r >> 1) & 3);          // pre-swizzled source
            const short* gsA = ga + (size_t)r * 1024 + js * 8;
            short* ldsA = &As[buf][0][0] + (size_t)(i * 256 + wv * 64) * 8;
            __builtin_amdgcn_global_load_lds((const __attribute__((address_space(1))) void*)gsA,
                                             (__attribute__((address_space(3))) void*)ldsA, 16, 0, 0);
        }
        {
            const int r = tid >> 2, jp = tid & 3;
            const int js = jp ^ ((r >> 1) & 3);
            const short* gsB = gb + (size_t)r * 1024 + js * 8;
            short* ldsB = &Bs[buf][0][0] + (size_t)(wv * 64) * 8;
            __builtin_amdgcn_global_load_lds((const __attribute__((address_space(1))) void*)gsB,
                                             (__attribute__((address_space(3))) void*)ldsB, 16, 0, 0);
        }
    };

    const int csw = (g ^ ((qc >> 1) & 3)) * 8;   // swizzled read chunk offset

    f32x4 acc[4][2] = {};
    stage(0, 0);
    __syncthreads();
    int cur = 0;
#pragma unroll 1
    for (int kb = 0; kb < 32; kb++) {
        if (kb < 31) stage(cur ^ 1, (kb + 1) * 32);
        short8 af[4], bfr[2];
#pragma unroll
        for (int mt = 0; mt < 4; mt++)
            af[mt] = *(const short8*)&As[cur][wm * 64 + mt * 16 + qc][csw];
#pragma unroll
        for (int nt = 0; nt < 2; nt++)
            bfr[nt] = *(const short8*)&Bs[cur][wn * 32 + nt * 16 + qc][csw];
#pragma unroll
        for (int mt = 0; mt < 4; mt++)
#pragma unroll
            for (int nt = 0; nt < 2; nt++)
                acc[mt][nt] = __builtin_amdgcn_mfma_f32_16x16x32_bf16(af[mt], bfr[nt], acc[mt][nt], 0, 0, 0);
        __syncthreads();
        cur ^= 1;
    }

    float bl[2];
#pragma unroll
    for (int nt = 0; nt < 2; nt++) bl[nt] = bias[Nb + wn * 32 + nt * 16 + qc];
#pragma unroll
    for (int mt = 0; mt < 4; mt++) {
#pragma unroll
        for (int nt = 0; nt < 2; nt++) {
            const int m0 = Mb + wm * 64 + mt * 16 + g * 4;
            const int n  = Nb + wn * 32 + nt * 16 + qc;
            f32x4 v = acc[mt][nt];
            v = v + bl[nt];
            if (EPI == 0) {
                const int bb = m0 >> 11, s0 = m0 & 2047;
                const int hh = n >> 6, dh = n & 63;
                uint2 p2;
                p2.x = cvt_pk_bf16(v[0], v[1]);
                p2.y = cvt_pk_bf16(v[2], v[3]);
                *(uint2*)((short*)Cout + (size_t)((bb * 16 + hh) * 64 + dh) * 2048 + s0) = p2;
            } else {
                float* C = (float*)Cout;
#pragma unroll
                for (int i = 0; i < 4; i++) C[(size_t)(m0 + i) * 1024 + n] = v[i];
            }
        }
    }
}

// ---------------------------------------------------------------------------
// Fused MFMA flash attention (v3): 16 queries/wave, 64 q/block, grid 1024
// blocks -> 4 blocks/CU, 4 waves/SIMD.  S = MFMA(ZA_k, ZB_q) = exp2 arg,
// p = exp2(min(S,0)), fixed m=0, l via ones-row MFMA.  V tile XOR-swizzled
// ((r&7) on chunk), Z tile XOR-swizzled ((r>>1)&3 on chunk) -> 2-way max.
// ---------------------------------------------------------------------------
__global__ __launch_bounds__(256, 4) void attn_mfma3(const short* __restrict__ ZAg,
                                                     const short* __restrict__ ZBg,
                                                     const short* __restrict__ Vt,
                                                     short* __restrict__ AOb) {
    __shared__ short Vs[2][64][64];
    __shared__ short Zs[2][64][32];
    const int tid = threadIdx.x;
    const int wv = tid >> 6, l = tid & 63, g = l >> 4, qc = l & 15;
    const int h = blockIdx.y, b = blockIdx.z;
    const int bh = b * 16 + h;
    const int q0 = blockIdx.x * 64 + wv * 16;

    const short* ZAb = ZAg + (size_t)bh * (2048 * 32);
    const short* ZBb = ZBg + (size_t)bh * (2048 * 32);
    const short* Vb  = Vt  + (size_t)bh * (64 * 2048);

    const short8 zq = *(const short8*)(ZBb + (size_t)(q0 + qc) * 32 + g * 8);

    union { unsigned u[4]; short8 s8; } onesf;
    {
        const unsigned ow = (qc == 0) ? 0x3F803F80u : 0u;   // row 0 of A-tile = ones
        onesf.u[0] = ow; onesf.u[1] = ow; onesf.u[2] = ow; onesf.u[3] = ow;
    }

    f32x4 acc[4] = {};
    f32x4 accl = {};

    // staging: V tile 64x64 (2 chunks/thread), Z tile 64x32 (1 chunk/thread)
    uint4 vr0, vr1, zr;
    const int v_r = tid >> 2, v_j = (tid & 3) * 2;
    const int z_r = tid >> 2, z_j = tid & 3;
    const int zsw = (z_j ^ ((z_r >> 1) & 3)) * 8;   // swizzled Z write pos

    auto tload = [&](int kb) {
        const short* p = Vb + (size_t)v_r * 2048 + kb + v_j * 8;
        vr0 = *(const uint4*)p;
        vr1 = *(const uint4*)(p + 8);
        zr = *(const uint4*)(ZAb + (size_t)(kb + z_r) * 32 + z_j * 8);
    };
    auto twrite = [&](int buf) {
        *(uint4*)&Vs[buf][v_r][(v_j ^ (v_r & 7)) * 8] = vr0;
        *(uint4*)&Vs[buf][v_r][((v_j + 1) ^ (v_r & 7)) * 8] = vr1;
        *(uint4*)&Zs[buf][z_r][zsw] = zr;
    };

    const int zrd = (g ^ ((qc >> 1) & 3)) * 8;      // swizzled Z read chunk

    tload(0);
    twrite(0);
    __syncthreads();
    int cur = 0;
#pragma unroll 1
    for (int kb = 0; kb < 2048; kb += 64) {
        const bool more = (kb + 64 < 2048);
        if (more) tload(kb + 64);   // issue early; written after compute

        short8 zk[4];
#pragma unroll
        for (int kt = 0; kt < 4; kt++)
            zk[kt] = *(const short8*)&Zs[cur][kt * 16 + qc][zrd];

        const f32x4 z4 = {0.f, 0.f, 0.f, 0.f};
        f32x4 S[4];
#pragma unroll
        for (int kt = 0; kt < 4; kt++)
            S[kt] = __builtin_amdgcn_mfma_f32_16x16x32_bf16(zk[kt], zq, z4, 0, 0, 0);

        // p = exp2(min(S,0)); pack to bf16 pairs
        unsigned pk[4][2];
#pragma unroll
        for (int kt = 0; kt < 4; kt++) {
            const float p0 = exp2_fast(fminf(S[kt][0], 0.f));
            const float p1 = exp2_fast(fminf(S[kt][1], 0.f));
            const float p2 = exp2_fast(fminf(S[kt][2], 0.f));
            const float p3 = exp2_fast(fminf(S[kt][3], 0.f));
            pk[kt][0] = cvt_pk_bf16(p0, p1);
            pk[kt][1] = cvt_pk_bf16(p2, p3);
        }

        // PV + l accumulation (D-layout -> B-frag redistribution)
#pragma unroll
        for (int s2 = 0; s2 < 2; s2++) {
            union { unsigned u[4]; short8 v8; } bfr;
#pragma unroll
            for (int w2 = 0; w2 < 4; w2++) {
                const int src = qc + 16 * (((g & 1) << 1) + (w2 >> 1));
                const int wi = w2 & 1;
                const unsigned u0 = (unsigned)__shfl((int)pk[s2 * 2 + 0][wi], src, 64);
                const unsigned u1 = (unsigned)__shfl((int)pk[s2 * 2 + 1][wi], src, 64);
                bfr.u[w2] = (g >> 1) ? u1 : u0;
            }
            short8 vf[4];
#pragma unroll
            for (int mt = 0; mt < 4; mt++)
                vf[mt] = *(const short8*)&Vs[cur][mt * 16 + qc][((s2 * 4 + g) ^ (qc & 7)) * 8];
            accl = __builtin_amdgcn_mfma_f32_16x16x32_bf16(onesf.s8, bfr.v8, accl, 0, 0, 0);
#pragma unroll
            for (int mt = 0; mt < 4; mt++)
                acc[mt] = __builtin_amdgcn_mfma_f32_16x16x32_bf16(vf[mt], bfr.v8, acc[mt], 0, 0, 0);
        }

        if (more) twrite(cur ^ 1);
        __syncthreads();
        cur ^= 1;
    }

    // epilogue: l sits at D(row0,col qc) = lane qc, reg 0
    const float lv = __shfl(accl[0], qc, 64);
    const float inv = 1.f / lv;
    const size_t row = (size_t)(b * 2048 + q0 + qc) * 1024 + h * 64;
#pragma unroll
    for (int mt = 0; mt < 4; mt++) {
        uint2 o;
        o.x = cvt_pk_bf16(acc[mt][0] * inv, acc[mt][1] * inv);
        o.y = cvt_pk_bf16(acc[mt][2] * inv, acc[mt][3] * inv);
        *(uint2*)(AOb + row + mt * 16 + g * 4) = o;
    }
}

// ---------------------------------------------------------------------------
// updated_coords = hidden @ Wn.T + bn (fp32 exact); 4 threads per output
// ---------------------------------------------------------------------------
__global__ __launch_bounds__(256) void coords_out2(const float* __restrict__ hs,
                                                   const float* __restrict__ Wn,
                                                   const float* __restrict__ bn,
                                                   float* __restrict__ out1) {
    const int gid = blockIdx.x * 256 + threadIdx.x;
    const int e = gid >> 2, sub = gid & 3;
    const int c = e & 15, bs = e >> 4;
    const float4* hrow = (const float4*)(hs + (size_t)bs * 1024) + sub * 64;
    const float4* wrow = (const float4*)(Wn + (size_t)c * 1024) + sub * 64;
    float acc = 0.f;
#pragma unroll 4
    for (int k = 0; k < 64; k++) {
        const float4 h4 = hrow[k], w4 = wrow[k];
        acc = fmaf(h4.x, w4.x, fmaf(h4.y, w4.y, fmaf(h4.z, w4.z, fmaf(h4.w, w4.w, acc))));
    }
    acc += __shfl_xor(acc, 1, 64);
    acc += __shfl_xor(acc, 2, 64);
    if (sub == 0) out1[e] = acc + bn[c];
}

// ---------------------------------------------------------------------------
extern "C" void kernel_launch(void* const* d_in, const int* in_sizes, int n_in,
                              void* d_out, int out_size, void* d_ws, size_t ws_size,
                              hipStream_t stream) {
    (void)in_sizes; (void)n_in; (void)out_size; (void)ws_size;
    const float* hidden = (const float*)d_in[0];
    const float* coords = (const float*)d_in[1];
    const float* Wv = (const float*)d_in[2];
    const float* bv = (const float*)d_in[3];
    const float* Wc = (const float*)d_in[4];
    const float* bc = (const float*)d_in[5];
    const float* Wn = (const float*)d_in[6];
    const float* bn = (const float*)d_in[7];
    const float* Wo = (const float*)d_in[8];
    const float* bo = (const float*)d_in[9];
    const float* gamma = (const float*)d_in[10];

    char* wsb = (char*)d_ws;
    short* hsb = (short*)(wsb);                    // 0..8 MB  [4096,1024] bf16
    short* AOb = hsb;                              // aliases hsb (hsb dead after gemm<0>)
    short* Wvb = (short*)(wsb + (8 << 20));        // 8..10 MB
    short* Wob = (short*)(wsb + (10 << 20));       // 10..12 MB
    short* Vt  = (short*)(wsb + (12 << 20));       // 12..20 MB [b,h,dh,s] bf16
    short* ZA  = (short*)(wsb + (20 << 20));       // 20..24 MB [b,h,s,32] bf16
    short* ZB  = (short*)(wsb + (24 << 20));       // 24..28 MB [b,h,s,32] bf16

    float* out_hidden = (float*)d_out;             // [B,S,D]
    float* out_coords = out_hidden + 4194304;      // [B,S,CD]

    f2bf_kernel<<<2048, 256, 0, stream>>>(hidden, hsb, 524288);
    f2bfW<<<1024, 256, 0, stream>>>(Wv, Wo, Wvb, Wob);
    zker3<<<4096, 256, 0, stream>>>(coords, Wc, bc, gamma, ZA, ZB);
    gemm_mfma<0><<<dim3(16, 32), 256, 0, stream>>>(hsb, Wvb, bv, (void*)Vt);
    attn_mfma3<<<dim3(32, 16, 2), 256, 0, stream>>>(ZA, ZB, Vt, AOb);
    gemm_mfma<1><<<dim3(16, 32), 256, 0, stream>>>(AOb, Wob, bo, (void*)out_hidden);
    coords_out2<<<1024, 256, 0, stream>>>(hidden, Wn, bn, out_coords);
}

// Round 5
// 168.881 us; speedup vs baseline: 7.4239x; 1.0508x over previous
//
#include <hip/hip_runtime.h>
#include <math.h>

// Problem constants: B=2, S=2048, D=1024, H=16, DC=16, DH=64
typedef short short8 __attribute__((ext_vector_type(8)));
typedef short short4t __attribute__((ext_vector_type(4)));
typedef float f32x4  __attribute__((ext_vector_type(4)));

__device__ __forceinline__ unsigned cvt_pk_bf16(float lo, float hi) {
    unsigned r;
    asm("v_cvt_pk_bf16_f32 %0, %1, %2" : "=v"(r) : "v"(lo), "v"(hi));
    return r;
}
__device__ __forceinline__ unsigned f2bf_rne(float x) {
    unsigned u = __float_as_uint(x);
    return (u + 0x7fffu + ((u >> 16) & 1u)) >> 16;
}
__device__ __forceinline__ float exp2_fast(float x) {   // v_exp_f32 computes 2^x
    float r;
    asm("v_exp_f32 %0, %1" : "=v"(r) : "v"(x));
    return r;
}
// 16x16x16 bf16 MFMA (K=16): B-frag layout matches the 16x16 D-layout of the
// score MFMA, so P needs NO cross-lane redistribution before PV.
__device__ __forceinline__ f32x4 mfma_k16(short4t a, short4t b, f32x4 c) {
#if __has_builtin(__builtin_amdgcn_mfma_f32_16x16x16bf16_1k)
    return __builtin_amdgcn_mfma_f32_16x16x16bf16_1k(a, b, c, 0, 0, 0);
#else
    asm volatile("v_mfma_f32_16x16x16_bf16 %0, %1, %2, %0" : "+v"(c) : "v"(a), "v"(b));
    return c;
#endif
}

// ---------------------------------------------------------------------------
// fp32 -> bf16 bulk convert (8 elems/thread)
// ---------------------------------------------------------------------------
__global__ __launch_bounds__(256) void f2bf_kernel(const float* __restrict__ in,
                                                   short* __restrict__ out, int n8) {
    const int i = blockIdx.x * 256 + threadIdx.x;
    if (i >= n8) return;
    const float4 a = ((const float4*)in)[2 * i];
    const float4 b = ((const float4*)in)[2 * i + 1];
    uint4 r;
    r.x = cvt_pk_bf16(a.x, a.y);
    r.y = cvt_pk_bf16(a.z, a.w);
    r.z = cvt_pk_bf16(b.x, b.y);
    r.w = cvt_pk_bf16(b.z, b.w);
    ((uint4*)out)[i] = r;
}

// both weight matrices in one launch (512 blocks each)
__global__ __launch_bounds__(256) void f2bfW(const float* __restrict__ Wv,
                                             const float* __restrict__ Wo,
                                             short* __restrict__ Wvb,
                                             short* __restrict__ Wob) {
    const int i = blockIdx.x * 256 + threadIdx.x;
    const float* src = (i < 131072) ? Wv : Wo;
    short* dst = (i < 131072) ? Wvb : Wob;
    const int ii = i & 131071;
    const float4 a = ((const float4*)src)[2 * ii];
    const float4 b = ((const float4*)src)[2 * ii + 1];
    uint4 r;
    r.x = cvt_pk_bf16(a.x, a.y);
    r.y = cvt_pk_bf16(a.z, a.w);
    r.z = cvt_pk_bf16(b.x, b.y);
    r.w = cvt_pk_bf16(b.z, b.w);
    ((uint4*)dst)[ii] = r;
}

// ---------------------------------------------------------------------------
// z = coords @ Wc.T + bc, per head h with ch = -softplus(gamma_h)*log2(e):
//   ZA[b,h,s,32] = [z(16), zsq, 1, 0...]          (keys / A-operand)
//   ZB[b,h,s,32] = [-2*ch*z(16), ch, ch*zsq, 0..] (queries / B-operand)
// => MFMA(ZA_k, ZB_q) = ch * (zsq_k + zsq_q - 2 z_k.z_q) = exp2 argument.
// ---------------------------------------------------------------------------
__global__ __launch_bounds__(256) void zker3(const float* __restrict__ coords,
                                             const float* __restrict__ Wc,
                                             const float* __restrict__ bc,
                                             const float* __restrict__ gamma,
                                             short* __restrict__ ZA,
                                             short* __restrict__ ZB) {
    const int bs = blockIdx.x;
    const int b = bs >> 11, s = bs & 2047;
    const int tid = threadIdx.x;
    __shared__ float csh[16];
    if (tid < 16) csh[tid] = coords[(size_t)bs * 16 + tid];
    __syncthreads();
    float z = bc[tid];
#pragma unroll
    for (int k = 0; k < 16; k++) z = fmaf(csh[k], Wc[tid * 16 + k], z);
    const unsigned ub = f2bf_rne(z);
    const float zb = __uint_as_float(ub << 16);
    float sq = zb * zb;
    sq += __shfl_xor(sq, 1, 64);
    sq += __shfl_xor(sq, 2, 64);
    sq += __shfl_xor(sq, 4, 64);
    sq += __shfl_xor(sq, 8, 64);
    const int h = tid >> 4, c = tid & 15;
    const float gm = gamma[h];
    const float sp = fmaxf(gm, 0.f) + log1pf(__expf(-fabsf(gm)));  // softplus
    const float ch = -sp * 1.4426950408889634f;                    // -g*log2(e)
    const size_t row = ((size_t)(b * 16 + h) * 2048 + s) * 32;
    ZA[row + c] = (short)ub;
    ZA[row + 16 + c] = (c == 0) ? (short)f2bf_rne(sq)
                                : (c == 1 ? (short)0x3F80 : (short)0);
    ZB[row + c] = (short)f2bf_rne(-2.f * ch * zb);
    ZB[row + 16 + c] = (c == 0) ? (short)f2bf_rne(ch)
                                : (c == 1 ? (short)f2bf_rne(ch * sq) : (short)0);
}

// ---------------------------------------------------------------------------
// bf16 MFMA GEMM: C[m,n] = sum_k A[m,k]*W[n,k] + bias[n].  M=4096,N=1024,K=1024
// 128x64 tile, BK=32, 4 waves (2x2 of 64x32), double-buffered LDS via
// global_load_lds w16; chunk-XOR swizzle via pre-swizzled global source.
// EPI=0: write V^T bf16 [b,h,dh,s];  EPI=1: fp32 row-major [m,n]
// ---------------------------------------------------------------------------
template <int EPI>
__global__ __launch_bounds__(256) void gemm_mfma(const short* __restrict__ A,
                                                 const short* __restrict__ W,
                                                 const float* __restrict__ bias,
                                                 void* __restrict__ Cout) {
    __shared__ short As[2][128][32];
    __shared__ short Bs[2][64][32];
    const int tid = threadIdx.x;
    const int wv = tid >> 6, l = tid & 63, g = l >> 4, qc = l & 15;
    const int wm = wv >> 1, wn = wv & 1;
    const int Mb = blockIdx.y * 128, Nb = blockIdx.x * 64;

    auto stage = [&](int buf, int k0) {
        const short* ga = A + (size_t)Mb * 1024 + k0;
        const short* gb = W + (size_t)Nb * 1024 + k0;
#pragma unroll
        for (int i = 0; i < 2; i++) {
            const int c = i * 256 + tid;                 // A chunk id 0..511
            const int r = c >> 2, jp = c & 3;
            const int js = jp ^ ((r >> 1) & 3);          // pre-swizzled source
            const short* gsA = ga + (size_t)r * 1024 + js * 8;
            short* ldsA = &As[buf][0][0] + (size_t)(i * 256 + wv * 64) * 8;
            __builtin_amdgcn_global_load_lds((const __attribute__((address_space(1))) void*)gsA,
                                             (__attribute__((address_space(3))) void*)ldsA, 16, 0, 0);
        }
        {
            const int r = tid >> 2, jp = tid & 3;
            const int js = jp ^ ((r >> 1) & 3);
            const short* gsB = gb + (size_t)r * 1024 + js * 8;
            short* ldsB = &Bs[buf][0][0] + (size_t)(wv * 64) * 8;
            __builtin_amdgcn_global_load_lds((const __attribute__((address_space(1))) void*)gsB,
                                             (__attribute__((address_space(3))) void*)ldsB, 16, 0, 0);
        }
    };

    const int csw = (g ^ ((qc >> 1) & 3)) * 8;   // swizzled read chunk offset

    f32x4 acc[4][2] = {};
    stage(0, 0);
    __syncthreads();
    int cur = 0;
#pragma unroll 1
    for (int kb = 0; kb < 32; kb++) {
        if (kb < 31) stage(cur ^ 1, (kb + 1) * 32);
        short8 af[4], bfr[2];
#pragma unroll
        for (int mt = 0; mt < 4; mt++)
            af[mt] = *(const short8*)&As[cur][wm * 64 + mt * 16 + qc][csw];
#pragma unroll
        for (int nt = 0; nt < 2; nt++)
            bfr[nt] = *(const short8*)&Bs[cur][wn * 32 + nt * 16 + qc][csw];
#pragma unroll
        for (int mt = 0; mt < 4; mt++)
#pragma unroll
            for (int nt = 0; nt < 2; nt++)
                acc[mt][nt] = __builtin_amdgcn_mfma_f32_16x16x32_bf16(af[mt], bfr[nt], acc[mt][nt], 0, 0, 0);
        __syncthreads();
        cur ^= 1;
    }

    float bl[2];
#pragma unroll
    for (int nt = 0; nt < 2; nt++) bl[nt] = bias[Nb + wn * 32 + nt * 16 + qc];
#pragma unroll
    for (int mt = 0; mt < 4; mt++) {
#pragma unroll
        for (int nt = 0; nt < 2; nt++) {
            const int m0 = Mb + wm * 64 + mt * 16 + g * 4;
            const int n  = Nb + wn * 32 + nt * 16 + qc;
            f32x4 v = acc[mt][nt];
            v = v + bl[nt];
            if (EPI == 0) {
                const int bb = m0 >> 11, s0 = m0 & 2047;
                const int hh = n >> 6, dh = n & 63;
                uint2 p2;
                p2.x = cvt_pk_bf16(v[0], v[1]);
                p2.y = cvt_pk_bf16(v[2], v[3]);
                *(uint2*)((short*)Cout + (size_t)((bb * 16 + hh) * 64 + dh) * 2048 + s0) = p2;
            } else {
                float* C = (float*)Cout;
#pragma unroll
                for (int i = 0; i < 4; i++) C[(size_t)(m0 + i) * 1024 + n] = v[i];
            }
        }
    }
}

// ---------------------------------------------------------------------------
// Fused MFMA flash attention (v4): 16 queries/wave, 64 q/block.
// Scores: S = MFMA_16x16x32(ZA_k, ZB_q) = exp2 arg; p = exp2(min(S,0));
// fixed m=0 (diagonal guarantees max 0); l via ones-row K=16 MFMA.
// PV: out^T[dh][q] via 4x v_mfma_f32_16x16x16_bf16 — the packed P words in
// score-D layout ARE the K=16 B-fragment, so no cross-lane redistribution.
// V^T A-frags are 8B LDS reads; 16B-chunk XOR swizzle -> throughput-floor.
// ---------------------------------------------------------------------------
__global__ __launch_bounds__(256, 4) void attn_mfma4(const short* __restrict__ ZAg,
                                                     const short* __restrict__ ZBg,
                                                     const short* __restrict__ Vt,
                                                     short* __restrict__ AOb) {
    __shared__ short Vs[2][64][64];
    __shared__ short Zs[2][64][32];
    const int tid = threadIdx.x;
    const int wv = tid >> 6, l = tid & 63, g = l >> 4, qc = l & 15;
    const int h = blockIdx.y, b = blockIdx.z;
    const int bh = b * 16 + h;
    const int q0 = blockIdx.x * 64 + wv * 16;

    const short* ZAb = ZAg + (size_t)bh * (2048 * 32);
    const short* ZBb = ZBg + (size_t)bh * (2048 * 32);
    const short* Vb  = Vt  + (size_t)bh * (64 * 2048);

    const short8 zq = *(const short8*)(ZBb + (size_t)(q0 + qc) * 32 + g * 8);

    union { unsigned u[2]; short4t s4; } ones4;
    ones4.u[0] = ones4.u[1] = (qc == 0) ? 0x3F803F80u : 0u;  // A row 0 = ones

    f32x4 acc[4] = {};
    f32x4 accl = {};

    // staging: V tile 64x64 (2 chunks/thread), Z tile 64x32 (1 chunk/thread)
    uint4 vr0, vr1, zr;
    const int v_r = tid >> 2, v_j = (tid & 3) * 2;
    const int z_r = tid >> 2, z_j = tid & 3;
    const int zsw = (z_j ^ ((z_r >> 1) & 3)) * 8;   // swizzled Z write pos

    auto tload = [&](int kb) {
        const short* p = Vb + (size_t)v_r * 2048 + kb + v_j * 8;
        vr0 = *(const uint4*)p;
        vr1 = *(const uint4*)(p + 8);
        zr = *(const uint4*)(ZAb + (size_t)(kb + z_r) * 32 + z_j * 8);
    };
    auto twrite = [&](int buf) {
        *(uint4*)&Vs[buf][v_r][(v_j ^ (v_r & 7)) * 8] = vr0;
        *(uint4*)&Vs[buf][v_r][((v_j + 1) ^ (v_r & 7)) * 8] = vr1;
        *(uint4*)&Zs[buf][z_r][zsw] = zr;
    };

    const int zrd = (g ^ ((qc >> 1) & 3)) * 8;      // swizzled Z read chunk

    tload(0);
    twrite(0);
    __syncthreads();
    int cur = 0;
#pragma unroll 1
    for (int kb = 0; kb < 2048; kb += 64) {
        const bool more = (kb + 64 < 2048);
        if (more) tload(kb + 64);   // issue early; written after compute

        short8 zk[4];
#pragma unroll
        for (int kt = 0; kt < 4; kt++)
            zk[kt] = *(const short8*)&Zs[cur][kt * 16 + qc][zrd];

        const f32x4 z4 = {0.f, 0.f, 0.f, 0.f};
        f32x4 S[4];
#pragma unroll
        for (int kt = 0; kt < 4; kt++)
            S[kt] = __builtin_amdgcn_mfma_f32_16x16x32_bf16(zk[kt], zq, z4, 0, 0, 0);

        // p = exp2(min(S,0)); pack -> per-kt B-fragment (D-layout == B-frag!)
        unsigned pk[4][2];
#pragma unroll
        for (int kt = 0; kt < 4; kt++) {
            const float p0 = exp2_fast(fminf(S[kt][0], 0.f));
            const float p1 = exp2_fast(fminf(S[kt][1], 0.f));
            const float p2 = exp2_fast(fminf(S[kt][2], 0.f));
            const float p3 = exp2_fast(fminf(S[kt][3], 0.f));
            pk[kt][0] = cvt_pk_bf16(p0, p1);
            pk[kt][1] = cvt_pk_bf16(p2, p3);
        }

        // PV + l via K=16 MFMAs: A = V^T[dh][16 keys of kt], B = pk[kt]
#pragma unroll
        for (int kt = 0; kt < 4; kt++) {
            union { unsigned u[2]; short4t s4; } pb;
            pb.u[0] = pk[kt][0];
            pb.u[1] = pk[kt][1];
            accl = mfma_k16(ones4.s4, pb.s4, accl);
            // V^T A-frag: row = mt*16+qc, 8B chunk c = kt*4+g, stored at
            // 16B chunk (c>>1)^(qc&7), 8B half c&1
            const short* vbase = &Vs[cur][qc][((((kt * 4 + g) >> 1) ^ (qc & 7)) << 3) + ((g & 1) << 2)];
#pragma unroll
            for (int mt = 0; mt < 4; mt++)
                acc[mt] = mfma_k16(*(const short4t*)(vbase + mt * 16 * 64), pb.s4, acc[mt]);
        }

        if (more) twrite(cur ^ 1);
        __syncthreads();
        cur ^= 1;
    }

    // epilogue: l sits at D(row0,col qc) = lane qc, reg 0
    const float lv = __shfl(accl[0], qc, 64);
    const float inv = 1.f / lv;
    const size_t row = (size_t)(b * 2048 + q0 + qc) * 1024 + h * 64;
#pragma unroll
    for (int mt = 0; mt < 4; mt++) {
        uint2 o;
        o.x = cvt_pk_bf16(acc[mt][0] * inv, acc[mt][1] * inv);
        o.y = cvt_pk_bf16(acc[mt][2] * inv, acc[mt][3] * inv);
        *(uint2*)(AOb + row + mt * 16 + g * 4) = o;
    }
}

// ---------------------------------------------------------------------------
// updated_coords = hidden @ Wn.T + bn (fp32 exact); 4 threads per output
// ---------------------------------------------------------------------------
__global__ __launch_bounds__(256) void coords_out2(const float* __restrict__ hs,
                                                   const float* __restrict__ Wn,
                                                   const float* __restrict__ bn,
                                                   float* __restrict__ out1) {
    const int gid = blockIdx.x * 256 + threadIdx.x;
    const int e = gid >> 2, sub = gid & 3;
    const int c = e & 15, bs = e >> 4;
    const float4* hrow = (const float4*)(hs + (size_t)bs * 1024) + sub * 64;
    const float4* wrow = (const float4*)(Wn + (size_t)c * 1024) + sub * 64;
    float acc = 0.f;
#pragma unroll 4
    for (int k = 0; k < 64; k++) {
        const float4 h4 = hrow[k], w4 = wrow[k];
        acc = fmaf(h4.x, w4.x, fmaf(h4.y, w4.y, fmaf(h4.z, w4.z, fmaf(h4.w, w4.w, acc))));
    }
    acc += __shfl_xor(acc, 1, 64);
    acc += __shfl_xor(acc, 2, 64);
    if (sub == 0) out1[e] = acc + bn[c];
}

// ---------------------------------------------------------------------------
extern "C" void kernel_launch(void* const* d_in, const int* in_sizes, int n_in,
                              void* d_out, int out_size, void* d_ws, size_t ws_size,
                              hipStream_t stream) {
    (void)in_sizes; (void)n_in; (void)out_size; (void)ws_size;
    const float* hidden = (const float*)d_in[0];
    const float* coords = (const float*)d_in[1];
    const float* Wv = (const float*)d_in[2];
    const float* bv = (const float*)d_in[3];
    const float* Wc = (const float*)d_in[4];
    const float* bc = (const float*)d_in[5];
    const float* Wn = (const float*)d_in[6];
    const float* bn = (const float*)d_in[7];
    const float* Wo = (const float*)d_in[8];
    const float* bo = (const float*)d_in[9];
    const float* gamma = (const float*)d_in[10];

    char* wsb = (char*)d_ws;
    short* hsb = (short*)(wsb);                    // 0..8 MB  [4096,1024] bf16
    short* AOb = hsb;                              // aliases hsb (hsb dead after gemm<0>)
    short* Wvb = (short*)(wsb + (8 << 20));        // 8..10 MB
    short* Wob = (short*)(wsb + (10 << 20));       // 10..12 MB
    short* Vt  = (short*)(wsb + (12 << 20));       // 12..20 MB [b,h,dh,s] bf16
    short* ZA  = (short*)(wsb + (20 << 20));       // 20..24 MB [b,h,s,32] bf16
    short* ZB  = (short*)(wsb + (24 << 20));       // 24..28 MB [b,h,s,32] bf16

    float* out_hidden = (float*)d_out;             // [B,S,D]
    float* out_coords = out_hidden + 4194304;      // [B,S,CD]

    f2bf_kernel<<<2048, 256, 0, stream>>>(hidden, hsb, 524288);
    f2bfW<<<1024, 256, 0, stream>>>(Wv, Wo, Wvb, Wob);
    zker3<<<4096, 256, 0, stream>>>(coords, Wc, bc, gamma, ZA, ZB);
    gemm_mfma<0><<<dim3(16, 32), 256, 0, stream>>>(hsb, Wvb, bv, (void*)Vt);
    attn_mfma4<<<dim3(32, 16, 2), 256, 0, stream>>>(ZA, ZB, Vt, AOb);
    gemm_mfma<1><<<dim3(16, 32), 256, 0, stream>>>(AOb, Wob, bo, (void*)out_hidden);
    coords_out2<<<1024, 256, 0, stream>>>(hidden, Wn, bn, out_coords);
}

// Round 6
// 118.470 us; speedup vs baseline: 10.5830x; 1.4255x over previous
//
#include <hip/hip_runtime.h>
#include <math.h>

// Problem constants: B=2, S=2048, D=1024, H=16, DC=16, DH=64
typedef short short8 __attribute__((ext_vector_type(8)));
typedef short short4t __attribute__((ext_vector_type(4)));
typedef float f32x4  __attribute__((ext_vector_type(4)));

__device__ __forceinline__ unsigned cvt_pk_bf16(float lo, float hi) {
    unsigned r;
    asm("v_cvt_pk_bf16_f32 %0, %1, %2" : "=v"(r) : "v"(lo), "v"(hi));
    return r;
}
__device__ __forceinline__ unsigned f2bf_rne(float x) {
    unsigned u = __float_as_uint(x);
    return (u + 0x7fffu + ((u >> 16) & 1u)) >> 16;
}
__device__ __forceinline__ float exp2_fast(float x) {   // v_exp_f32 computes 2^x
    float r;
    asm("v_exp_f32 %0, %1" : "=v"(r) : "v"(x));
    return r;
}
// 16x16x16 bf16 MFMA (K=16): B-frag layout matches the 16x16 D-layout of the
// score MFMA, so P needs NO cross-lane redistribution before PV.
__device__ __forceinline__ f32x4 mfma_k16(short4t a, short4t b, f32x4 c) {
#if __has_builtin(__builtin_amdgcn_mfma_f32_16x16x16bf16_1k)
    return __builtin_amdgcn_mfma_f32_16x16x16bf16_1k(a, b, c, 0, 0, 0);
#else
    asm volatile("v_mfma_f32_16x16x16_bf16 %0, %1, %2, %0" : "+v"(c) : "v"(a), "v"(b));
    return c;
#endif
}

// ---------------------------------------------------------------------------
// fp32 -> bf16 bulk convert (8 elems/thread)
// ---------------------------------------------------------------------------
__global__ __launch_bounds__(256) void f2bf_kernel(const float* __restrict__ in,
                                                   short* __restrict__ out, int n8) {
    const int i = blockIdx.x * 256 + threadIdx.x;
    if (i >= n8) return;
    const float4 a = ((const float4*)in)[2 * i];
    const float4 b = ((const float4*)in)[2 * i + 1];
    uint4 r;
    r.x = cvt_pk_bf16(a.x, a.y);
    r.y = cvt_pk_bf16(a.z, a.w);
    r.z = cvt_pk_bf16(b.x, b.y);
    r.w = cvt_pk_bf16(b.z, b.w);
    ((uint4*)out)[i] = r;
}

// Wv, Wo, Wn weight converts in one launch (grid 1032)
__global__ __launch_bounds__(256) void f2bfW(const float* __restrict__ Wv,
                                             const float* __restrict__ Wo,
                                             const float* __restrict__ Wn,
                                             short* __restrict__ Wvb,
                                             short* __restrict__ Wob,
                                             short* __restrict__ Wnb) {
    const int i = blockIdx.x * 256 + threadIdx.x;
    const float* src;
    short* dst;
    int ii;
    if (i < 131072)      { src = Wv; dst = Wvb; ii = i; }
    else if (i < 262144) { src = Wo; dst = Wob; ii = i - 131072; }
    else                 { src = Wn; dst = Wnb; ii = i - 262144; }
    const float4 a = ((const float4*)src)[2 * ii];
    const float4 b = ((const float4*)src)[2 * ii + 1];
    uint4 r;
    r.x = cvt_pk_bf16(a.x, a.y);
    r.y = cvt_pk_bf16(a.z, a.w);
    r.z = cvt_pk_bf16(b.x, b.y);
    r.w = cvt_pk_bf16(b.z, b.w);
    ((uint4*)dst)[ii] = r;
}

// ---------------------------------------------------------------------------
// z = coords @ Wc.T + bc, per head h with ch = -softplus(gamma_h)*log2(e):
//   ZA[b,h,s,32] = [z(16), zsq, 1, 0...]          (keys / A-operand)
//   ZB[b,h,s,32] = [-2*ch*z(16), ch, ch*zsq, 0..] (queries / B-operand)
// => MFMA(ZA_k, ZB_q) = ch * (zsq_k + zsq_q - 2 z_k.z_q) = exp2 argument.
// ---------------------------------------------------------------------------
__global__ __launch_bounds__(256) void zker3(const float* __restrict__ coords,
                                             const float* __restrict__ Wc,
                                             const float* __restrict__ bc,
                                             const float* __restrict__ gamma,
                                             short* __restrict__ ZA,
                                             short* __restrict__ ZB) {
    const int bs = blockIdx.x;
    const int b = bs >> 11, s = bs & 2047;
    const int tid = threadIdx.x;
    __shared__ float csh[16];
    if (tid < 16) csh[tid] = coords[(size_t)bs * 16 + tid];
    __syncthreads();
    float z = bc[tid];
#pragma unroll
    for (int k = 0; k < 16; k++) z = fmaf(csh[k], Wc[tid * 16 + k], z);
    const unsigned ub = f2bf_rne(z);
    const float zb = __uint_as_float(ub << 16);
    float sq = zb * zb;
    sq += __shfl_xor(sq, 1, 64);
    sq += __shfl_xor(sq, 2, 64);
    sq += __shfl_xor(sq, 4, 64);
    sq += __shfl_xor(sq, 8, 64);
    const int h = tid >> 4, c = tid & 15;
    const float gm = gamma[h];
    const float sp = fmaxf(gm, 0.f) + log1pf(__expf(-fabsf(gm)));  // softplus
    const float ch = -sp * 1.4426950408889634f;                    // -g*log2(e)
    const size_t row = ((size_t)(b * 16 + h) * 2048 + s) * 32;
    ZA[row + c] = (short)ub;
    ZA[row + 16 + c] = (c == 0) ? (short)f2bf_rne(sq)
                                : (c == 1 ? (short)0x3F80 : (short)0);
    ZB[row + c] = (short)f2bf_rne(-2.f * ch * zb);
    ZB[row + 16 + c] = (c == 0) ? (short)f2bf_rne(ch)
                                : (c == 1 ? (short)f2bf_rne(ch * sq) : (short)0);
}

// ---------------------------------------------------------------------------
// bf16 MFMA GEMM: C[m,n] = sum_k A[m,k]*W[n,k] + bias[n].  M=4096,N=1024,K=1024
// 128x64 tile, BK=32, 4 waves (2x2 of 64x32), double-buffered LDS via
// global_load_lds w16; chunk-XOR swizzle via pre-swizzled global source.
// EPI=0: write V^T bf16 [b,h,dh,s];  EPI=1: fp32 row-major [m,n]
// ---------------------------------------------------------------------------
template <int EPI>
__global__ __launch_bounds__(256) void gemm_mfma(const short* __restrict__ A,
                                                 const short* __restrict__ W,
                                                 const float* __restrict__ bias,
                                                 void* __restrict__ Cout) {
    __shared__ short As[2][128][32];
    __shared__ short Bs[2][64][32];
    const int tid = threadIdx.x;
    const int wv = tid >> 6, l = tid & 63, g = l >> 4, qc = l & 15;
    const int wm = wv >> 1, wn = wv & 1;
    const int Mb = blockIdx.y * 128, Nb = blockIdx.x * 64;

    auto stage = [&](int buf, int k0) {
        const short* ga = A + (size_t)Mb * 1024 + k0;
        const short* gb = W + (size_t)Nb * 1024 + k0;
#pragma unroll
        for (int i = 0; i < 2; i++) {
            const int c = i * 256 + tid;                 // A chunk id 0..511
            const int r = c >> 2, jp = c & 3;
            const int js = jp ^ ((r >> 1) & 3);          // pre-swizzled source
            const short* gsA = ga + (size_t)r * 1024 + js * 8;
            short* ldsA = &As[buf][0][0] + (size_t)(i * 256 + wv * 64) * 8;
            __builtin_amdgcn_global_load_lds((const __attribute__((address_space(1))) void*)gsA,
                                             (__attribute__((address_space(3))) void*)ldsA, 16, 0, 0);
        }
        {
            const int r = tid >> 2, jp = tid & 3;
            const int js = jp ^ ((r >> 1) & 3);
            const short* gsB = gb + (size_t)r * 1024 + js * 8;
            short* ldsB = &Bs[buf][0][0] + (size_t)(wv * 64) * 8;
            __builtin_amdgcn_global_load_lds((const __attribute__((address_space(1))) void*)gsB,
                                             (__attribute__((address_space(3))) void*)ldsB, 16, 0, 0);
        }
    };

    const int csw = (g ^ ((qc >> 1) & 3)) * 8;   // swizzled read chunk offset

    f32x4 acc[4][2] = {};
    stage(0, 0);
    __syncthreads();
    int cur = 0;
#pragma unroll 1
    for (int kb = 0; kb < 32; kb++) {
        if (kb < 31) stage(cur ^ 1, (kb + 1) * 32);
        short8 af[4], bfr[2];
#pragma unroll
        for (int mt = 0; mt < 4; mt++)
            af[mt] = *(const short8*)&As[cur][wm * 64 + mt * 16 + qc][csw];
#pragma unroll
        for (int nt = 0; nt < 2; nt++)
            bfr[nt] = *(const short8*)&Bs[cur][wn * 32 + nt * 16 + qc][csw];
#pragma unroll
        for (int mt = 0; mt < 4; mt++)
#pragma unroll
            for (int nt = 0; nt < 2; nt++)
                acc[mt][nt] = __builtin_amdgcn_mfma_f32_16x16x32_bf16(af[mt], bfr[nt], acc[mt][nt], 0, 0, 0);
        __syncthreads();
        cur ^= 1;
    }

    float bl[2];
#pragma unroll
    for (int nt = 0; nt < 2; nt++) bl[nt] = bias[Nb + wn * 32 + nt * 16 + qc];
#pragma unroll
    for (int mt = 0; mt < 4; mt++) {
#pragma unroll
        for (int nt = 0; nt < 2; nt++) {
            const int m0 = Mb + wm * 64 + mt * 16 + g * 4;
            const int n  = Nb + wn * 32 + nt * 16 + qc;
            f32x4 v = acc[mt][nt];
            v = v + bl[nt];
            if (EPI == 0) {
                const int bb = m0 >> 11, s0 = m0 & 2047;
                const int hh = n >> 6, dh = n & 63;
                uint2 p2;
                p2.x = cvt_pk_bf16(v[0], v[1]);
                p2.y = cvt_pk_bf16(v[2], v[3]);
                *(uint2*)((short*)Cout + (size_t)((bb * 16 + hh) * 64 + dh) * 2048 + s0) = p2;
            } else {
                float* C = (float*)Cout;
#pragma unroll
                for (int i = 0; i < 4; i++) C[(size_t)(m0 + i) * 1024 + n] = v[i];
            }
        }
    }
}

// ---------------------------------------------------------------------------
// Fused MFMA flash attention (v4 + setprio): 16 queries/wave, 64 q/block.
// ---------------------------------------------------------------------------
__global__ __launch_bounds__(256, 4) void attn_mfma4(const short* __restrict__ ZAg,
                                                     const short* __restrict__ ZBg,
                                                     const short* __restrict__ Vt,
                                                     short* __restrict__ AOb) {
    __shared__ short Vs[2][64][64];
    __shared__ short Zs[2][64][32];
    const int tid = threadIdx.x;
    const int wv = tid >> 6, l = tid & 63, g = l >> 4, qc = l & 15;
    const int h = blockIdx.y, b = blockIdx.z;
    const int bh = b * 16 + h;
    const int q0 = blockIdx.x * 64 + wv * 16;

    const short* ZAb = ZAg + (size_t)bh * (2048 * 32);
    const short* ZBb = ZBg + (size_t)bh * (2048 * 32);
    const short* Vb  = Vt  + (size_t)bh * (64 * 2048);

    const short8 zq = *(const short8*)(ZBb + (size_t)(q0 + qc) * 32 + g * 8);

    union { unsigned u[2]; short4t s4; } ones4;
    ones4.u[0] = ones4.u[1] = (qc == 0) ? 0x3F803F80u : 0u;  // A row 0 = ones

    f32x4 acc[4] = {};
    f32x4 accl = {};

    uint4 vr0, vr1, zr;
    const int v_r = tid >> 2, v_j = (tid & 3) * 2;
    const int z_r = tid >> 2, z_j = tid & 3;
    const int zsw = (z_j ^ ((z_r >> 1) & 3)) * 8;   // swizzled Z write pos

    auto tload = [&](int kb) {
        const short* p = Vb + (size_t)v_r * 2048 + kb + v_j * 8;
        vr0 = *(const uint4*)p;
        vr1 = *(const uint4*)(p + 8);
        zr = *(const uint4*)(ZAb + (size_t)(kb + z_r) * 32 + z_j * 8);
    };
    auto twrite = [&](int buf) {
        *(uint4*)&Vs[buf][v_r][(v_j ^ (v_r & 7)) * 8] = vr0;
        *(uint4*)&Vs[buf][v_r][((v_j + 1) ^ (v_r & 7)) * 8] = vr1;
        *(uint4*)&Zs[buf][z_r][zsw] = zr;
    };

    const int zrd = (g ^ ((qc >> 1) & 3)) * 8;      // swizzled Z read chunk

    tload(0);
    twrite(0);
    __syncthreads();
    int cur = 0;
#pragma unroll 1
    for (int kb = 0; kb < 2048; kb += 64) {
        const bool more = (kb + 64 < 2048);
        if (more) tload(kb + 64);   // issue early; written after compute

        short8 zk[4];
#pragma unroll
        for (int kt = 0; kt < 4; kt++)
            zk[kt] = *(const short8*)&Zs[cur][kt * 16 + qc][zrd];

        const f32x4 z4 = {0.f, 0.f, 0.f, 0.f};
        f32x4 S[4];
        __builtin_amdgcn_s_setprio(1);
#pragma unroll
        for (int kt = 0; kt < 4; kt++)
            S[kt] = __builtin_amdgcn_mfma_f32_16x16x32_bf16(zk[kt], zq, z4, 0, 0, 0);
        __builtin_amdgcn_s_setprio(0);

        unsigned pk[4][2];
#pragma unroll
        for (int kt = 0; kt < 4; kt++) {
            const float p0 = exp2_fast(fminf(S[kt][0], 0.f));
            const float p1 = exp2_fast(fminf(S[kt][1], 0.f));
            const float p2 = exp2_fast(fminf(S[kt][2], 0.f));
            const float p3 = exp2_fast(fminf(S[kt][3], 0.f));
            pk[kt][0] = cvt_pk_bf16(p0, p1);
            pk[kt][1] = cvt_pk_bf16(p2, p3);
        }

        __builtin_amdgcn_s_setprio(1);
#pragma unroll
        for (int kt = 0; kt < 4; kt++) {
            union { unsigned u[2]; short4t s4; } pb;
            pb.u[0] = pk[kt][0];
            pb.u[1] = pk[kt][1];
            accl = mfma_k16(ones4.s4, pb.s4, accl);
            const short* vbase = &Vs[cur][qc][((((kt * 4 + g) >> 1) ^ (qc & 7)) << 3) + ((g & 1) << 2)];
#pragma unroll
            for (int mt = 0; mt < 4; mt++)
                acc[mt] = mfma_k16(*(const short4t*)(vbase + mt * 16 * 64), pb.s4, acc[mt]);
        }
        __builtin_amdgcn_s_setprio(0);

        if (more) twrite(cur ^ 1);
        __syncthreads();
        cur ^= 1;
    }

    const float lv = __shfl(accl[0], qc, 64);
    const float inv = 1.f / lv;
    const size_t row = (size_t)(b * 2048 + q0 + qc) * 1024 + h * 64;
#pragma unroll
    for (int mt = 0; mt < 4; mt++) {
        uint2 o;
        o.x = cvt_pk_bf16(acc[mt][0] * inv, acc[mt][1] * inv);
        o.y = cvt_pk_bf16(acc[mt][2] * inv, acc[mt][3] * inv);
        *(uint2*)(AOb + row + mt * 16 + g * 4) = o;
    }
}

// ---------------------------------------------------------------------------
// updated_coords = hsb(bf16) @ Wnb.T + bn via MFMA.  M=4096, N=16, K=1024.
// 256 blocks; block = 16 rows; 4 waves split K (256 each, 8 MFMAs); LDS
// 4-way reduce; fp32 epilogue.  Runs BEFORE attn overwrites hsb (AOb alias).
// ---------------------------------------------------------------------------
__global__ __launch_bounds__(256) void coords_mfma(const short* __restrict__ A,
                                                   const short* __restrict__ Wnb,
                                                   const float* __restrict__ bn,
                                                   float* __restrict__ out1) {
    __shared__ float red[4][16][16];
    const int tid = threadIdx.x;
    const int wv = tid >> 6, l = tid & 63, g = l >> 4, qc = l & 15;
    const int m0 = blockIdx.x * 16;
    const int k0 = wv * 256;
    f32x4 acc = {};
#pragma unroll
    for (int kk = 0; kk < 256; kk += 32) {
        const short8 af = *(const short8*)(A + (size_t)(m0 + qc) * 1024 + k0 + kk + g * 8);
        const short8 bf = *(const short8*)(Wnb + (size_t)qc * 1024 + k0 + kk + g * 8);
        acc = __builtin_amdgcn_mfma_f32_16x16x32_bf16(af, bf, acc, 0, 0, 0);
    }
#pragma unroll
    for (int i2 = 0; i2 < 4; i2++) red[wv][g * 4 + i2][qc] = acc[i2];
    __syncthreads();
    const int r = tid >> 4, c = tid & 15;
    const float s = red[0][r][c] + red[1][r][c] + red[2][r][c] + red[3][r][c] + bn[c];
    out1[(size_t)(m0 + r) * 16 + c] = s;
}

// ---------------------------------------------------------------------------
extern "C" void kernel_launch(void* const* d_in, const int* in_sizes, int n_in,
                              void* d_out, int out_size, void* d_ws, size_t ws_size,
                              hipStream_t stream) {
    (void)in_sizes; (void)n_in; (void)out_size; (void)ws_size;
    const float* hidden = (const float*)d_in[0];
    const float* coords = (const float*)d_in[1];
    const float* Wv = (const float*)d_in[2];
    const float* bv = (const float*)d_in[3];
    const float* Wc = (const float*)d_in[4];
    const float* bc = (const float*)d_in[5];
    const float* Wn = (const float*)d_in[6];
    const float* bn = (const float*)d_in[7];
    const float* Wo = (const float*)d_in[8];
    const float* bo = (const float*)d_in[9];
    const float* gamma = (const float*)d_in[10];

    char* wsb = (char*)d_ws;
    short* hsb = (short*)(wsb);                    // 0..8 MB  [4096,1024] bf16
    short* AOb = hsb;                              // aliases hsb (hsb dead after coords_mfma)
    short* Wvb = (short*)(wsb + (8 << 20));        // 8..10 MB
    short* Wob = (short*)(wsb + (10 << 20));       // 10..12 MB
    short* Vt  = (short*)(wsb + (12 << 20));       // 12..20 MB [b,h,dh,s] bf16
    short* ZA  = (short*)(wsb + (20 << 20));       // 20..24 MB [b,h,s,32] bf16
    short* ZB  = (short*)(wsb + (24 << 20));       // 24..28 MB [b,h,s,32] bf16
    short* Wnb = (short*)(wsb + (28 << 20));       // 28 MB + 32 KB [16,1024] bf16

    float* out_hidden = (float*)d_out;             // [B,S,D]
    float* out_coords = out_hidden + 4194304;      // [B,S,CD]

    f2bf_kernel<<<2048, 256, 0, stream>>>(hidden, hsb, 524288);
    f2bfW<<<1032, 256, 0, stream>>>(Wv, Wo, Wn, Wvb, Wob, Wnb);
    zker3<<<4096, 256, 0, stream>>>(coords, Wc, bc, gamma, ZA, ZB);
    gemm_mfma<0><<<dim3(16, 32), 256, 0, stream>>>(hsb, Wvb, bv, (void*)Vt);
    coords_mfma<<<256, 256, 0, stream>>>(hsb, Wnb, bn, out_coords);
    attn_mfma4<<<dim3(32, 16, 2), 256, 0, stream>>>(ZA, ZB, Vt, AOb);
    gemm_mfma<1><<<dim3(16, 32), 256, 0, stream>>>(AOb, Wob, bo, (void*)out_hidden);
}